// Round 2
// baseline (45615.228 us; speedup 1.0000x reference)
//
#include <hip/hip_runtime.h>
#include <hip/hip_fp16.h>
#include <math.h>

// ---------- types ----------
typedef _Float16 h2 __attribute__((ext_vector_type(2)));
typedef _Float16 h8 __attribute__((ext_vector_type(8)));
typedef float    f4 __attribute__((ext_vector_type(4)));

// ---------- problem dims ----------
#define BB 64
#define TT 512
#define DD 256
#define UU 512
#define NG 2816   // 4U (fs,fl,al,o) + D (m) + U (c_pre from W_C h-rows)
#define NX 2304   // columns that get an x contribution
#define KH 512    // recurrent K (h only)

// ---------- ws layout (bytes) ----------
#define OFF_W1T   0u                                   // f16 [2816][512]  K-contiguous
#define OFF_W2T   (2816u*512u*2u)                      // f16 [512][256]
#define OFF_WXT   (OFF_W2T + 512u*256u*2u)             // f16 [2304][256]
#define OFF_B1    (OFF_WXT + 2304u*256u*2u)            // f32 [2816]
#define OFF_XPRE  (OFF_B1 + 2816u*4u)                  // f16 [32768][2304]
#define WS_MIN    (OFF_XPRE)                                       // fallback needs this much
#define WS_FULL   (OFF_XPRE + (size_t)32768u*2304u*2u)             // ~155.3 MB

__device__ __forceinline__ float sigf(float v) { return 1.0f / (1.0f + expf(-v)); }

// =====================================================================
// Kernel 1: repack weights (fp32 row-major -> f16 K-contiguous) + biases
// =====================================================================
__global__ void repack_kernel(const float* __restrict__ Wfs, const float* __restrict__ Wfl,
                              const float* __restrict__ Wal, const float* __restrict__ Wm,
                              const float* __restrict__ WC,  const float* __restrict__ Wo,
                              const float* __restrict__ bfs, const float* __restrict__ bfl,
                              const float* __restrict__ bal, const float* __restrict__ bm,
                              const float* __restrict__ bC,  const float* __restrict__ bo,
                              _Float16* __restrict__ W1t, _Float16* __restrict__ W2t,
                              _Float16* __restrict__ WxT, float* __restrict__ b1)
{
    const int stride = gridDim.x * blockDim.x;
    const int idx = blockIdx.x * blockDim.x + threadIdx.x;
    const int N1 = 2816 * 512, N2 = 512 * 256, N3 = 2304 * 256;

    // W1t[j][k] = W_h[k][j]  (h rows only, k<512)
    for (int i = idx; i < N1; i += stride) {
        int j = i >> 9, k = i & 511;
        float v;
        if      (j < 512)  v = Wfs[k * 512 + j];
        else if (j < 1024) v = Wfl[k * 512 + (j - 512)];
        else if (j < 1536) v = Wal[k * 512 + (j - 1024)];
        else if (j < 2048) v = Wo [k * 512 + (j - 1536)];
        else if (j < 2304) v = Wm [k * 256 + (j - 2048)];
        else               v = WC [k * 512 + (j - 2304)];
        W1t[i] = (_Float16)v;
    }
    // W2t[j][k] = W_C[512+k][j]  (mod_x rows)
    for (int i = idx; i < N2; i += stride) {
        int j = i >> 8, k = i & 255;
        W2t[i] = (_Float16)WC[(512 + k) * 512 + j];
    }
    // WxT[j][k] = W_x[k][j]  (x rows of the 2304 gate cols)
    for (int i = idx; i < N3; i += stride) {
        int j = i >> 8, k = i & 255;
        int r = 512 + k;
        float v;
        if      (j < 512)  v = Wfs[r * 512 + j];
        else if (j < 1024) v = Wfl[r * 512 + (j - 512)];
        else if (j < 1536) v = Wal[r * 512 + (j - 1024)];
        else if (j < 2048) v = Wo [r * 512 + (j - 1536)];
        else               v = Wm [r * 256 + (j - 2048)];
        WxT[i] = (_Float16)v;
    }
    // b1
    for (int i = idx; i < 2816; i += stride) {
        float v;
        if      (i < 512)  v = bfs[i];
        else if (i < 1024) v = bfl[i - 512];
        else if (i < 1536) v = bal[i - 1024];
        else if (i < 2048) v = bo [i - 1536];
        else if (i < 2304) v = bm [i - 2048];
        else               v = bC [i - 2304];
        b1[i] = v;
    }
}

// =====================================================================
// Kernel 2: Xpre = x @ W_x  via MFMA f16.  [32768,256]@[256,2304] -> f16
// tile 128x128, BK=32, 4 waves (2x2), each wave 64x64 (4x4 frags)
// =====================================================================
__global__ __launch_bounds__(256) void xpre_kernel(const float* __restrict__ x,
                                                   const _Float16* __restrict__ WxT,
                                                   _Float16* __restrict__ Xpre)
{
    __shared__ _Float16 As[128 * 32];
    __shared__ _Float16 Bs[128 * 32];

    const int tid  = threadIdx.x;
    const int lane = tid & 63;
    const int w    = tid >> 6;
    const int wm   = w >> 1, wn = w & 1;
    const int quad = lane >> 4, l16 = lane & 15;
    const int row0 = blockIdx.x * 128;
    const int n0   = blockIdx.y * 128;

    f4 acc[4][4];
    for (int i = 0; i < 4; ++i)
        for (int j = 0; j < 4; ++j)
            acc[i][j] = (f4){0.f, 0.f, 0.f, 0.f};

    for (int kt = 0; kt < 8; ++kt) {
        const int k0 = kt * 32;
        // stage A (x fp32 -> f16 LDS), 128 rows x 32 cols
        {
            int r  = tid >> 3;
            int cg = (tid & 7) * 4;
            for (int rr = r; rr < 128; rr += 32) {
                f4 v = *(const f4*)&x[(size_t)(row0 + rr) * 256 + k0 + cg];
                As[rr * 32 + cg + 0] = (_Float16)v.x;
                As[rr * 32 + cg + 1] = (_Float16)v.y;
                As[rr * 32 + cg + 2] = (_Float16)v.z;
                As[rr * 32 + cg + 3] = (_Float16)v.w;
            }
        }
        // stage B (WxT f16 copy), 128 rows x 32 k
        {
            int r   = tid & 127;
            int seg = (tid >> 7) * 16;  // halfs
            const _Float16* src = &WxT[(size_t)(n0 + r) * 256 + k0 + seg];
            *(f4*)&Bs[r * 32 + seg]     = *(const f4*)src;
            *(f4*)&Bs[r * 32 + seg + 8] = *(const f4*)(src + 8);
        }
        __syncthreads();

        h8 af[4], bf[4];
#pragma unroll
        for (int f = 0; f < 4; ++f) {
            af[f] = *(const h8*)&As[(wm * 64 + f * 16 + l16) * 32 + quad * 8];
            bf[f] = *(const h8*)&Bs[(wn * 64 + f * 16 + l16) * 32 + quad * 8];
        }
#pragma unroll
        for (int fm = 0; fm < 4; ++fm)
#pragma unroll
            for (int fn = 0; fn < 4; ++fn)
                acc[fm][fn] = __builtin_amdgcn_mfma_f32_16x16x32_f16(af[fm], bf[fn], acc[fm][fn], 0, 0, 0);
        __syncthreads();
    }

    // store D: col = lane&15, row = quad*4 + reg
#pragma unroll
    for (int fm = 0; fm < 4; ++fm) {
#pragma unroll
        for (int fn = 0; fn < 4; ++fn) {
            int n  = n0 + wn * 64 + fn * 16 + l16;
            int m0 = row0 + wm * 64 + fm * 16 + quad * 4;
#pragma unroll
            for (int r = 0; r < 4; ++r)
                Xpre[(size_t)(m0 + r) * 2304 + n] = (_Float16)acc[fm][fn][r];
        }
    }
}

// =====================================================================
// Kernel 3: recurrent scan. One block per batch, 704 threads (11 waves).
// Each thread owns 4 consecutive output columns of the 2816-wide GEMM1.
// XP=true: x-contribution comes from precomputed Xpre (needs 151MB ws).
// XP=false: x-contribution computed in-loop via WxT (K=256) — small-ws fallback.
// =====================================================================
template <bool XP>
__global__ __launch_bounds__(704) void rnn_kernel(const float* __restrict__ x,
                                                  const float* __restrict__ h0,
                                                  const float* __restrict__ c0,
                                                  const _Float16* __restrict__ W1t,
                                                  const _Float16* __restrict__ W2t,
                                                  const _Float16* __restrict__ WxT,
                                                  const float* __restrict__ b1g,
                                                  const _Float16* __restrict__ Xpre,
                                                  float* __restrict__ out)
{
    __shared__ float g_ld[2816];
    __shared__ float b1_ld[2816];
    __shared__ float h_ld[512];
    __shared__ float x_ld[256];
    __shared__ float f_ld[512];
    __shared__ float o_ld[512];
    __shared__ float c_ld[512];
    __shared__ __align__(16) h2 hx_h2[256];    // h packed as f16 pairs (K=512)
    __shared__ __align__(16) h2 x16_h2[128];   // x packed as f16 pairs (fallback path)
    __shared__ __align__(16) h2 modx_h2[128];  // mod_x packed (K=256)

    const int tid = threadIdx.x;
    const int b   = blockIdx.x;
    const int j0  = tid * 4;

    for (int j = tid; j < 2816; j += 704) b1_ld[j] = b1g[j];
    if (tid < 512) {
        h_ld[tid] = h0[b * 512 + tid];
        c_ld[tid] = c0[b * 512 + tid];
    }
    __syncthreads();

    const f4* __restrict__ w1r = (const f4*)(W1t + (size_t)j0 * 512);  // 4 rows, stride 64 f4
    const float* __restrict__ xrow = x + (size_t)b * TT * DD;
    float* __restrict__ orow = out + (size_t)b * TT * UU;
    const _Float16* __restrict__ xprow = XP ? (Xpre + (size_t)b * TT * NX) : (const _Float16*)nullptr;

    for (int t = 0; t < TT; ++t) {
        // ---- pack h to f16 pairs; load x_t ----
        if (tid < 256) {
            h2 p;
            p[0] = (_Float16)h_ld[2 * tid];
            p[1] = (_Float16)h_ld[2 * tid + 1];
            hx_h2[tid] = p;
        } else if (XP) {
            if (tid < 512) x_ld[tid - 256] = xrow[t * DD + (tid - 256)];
        } else {
            if (tid < 384) {
                int i = tid - 256;
                float v0 = xrow[t * DD + 2 * i];
                float v1 = xrow[t * DD + 2 * i + 1];
                x_ld[2 * i] = v0;
                x_ld[2 * i + 1] = v1;
                h2 p;
                p[0] = (_Float16)v0;
                p[1] = (_Float16)v1;
                x16_h2[i] = p;
            }
        }
        __syncthreads();

        // ---- GEMM1: gates/c_pre = h @ W1 (+ x-part + b) ----
        float a0 = b1_ld[j0], a1 = b1_ld[j0 + 1], a2 = b1_ld[j0 + 2], a3 = b1_ld[j0 + 3];
        if (XP) {
            if (j0 < NX) {
                const _Float16* xp = xprow + (size_t)t * NX + j0;
                a0 += (float)xp[0]; a1 += (float)xp[1]; a2 += (float)xp[2]; a3 += (float)xp[3];
            }
        } else {
            if (j0 < NX) {
                const f4* xr0 = (const f4*)(WxT + (size_t)j0 * 256);
                const f4* xr1 = xr0 + 32;
                const f4* xr2 = xr0 + 64;
                const f4* xr3 = xr0 + 96;
                const f4* xv4 = (const f4*)x16_h2;  // 32 x f4
#pragma unroll 4
                for (int kc = 0; kc < 32; ++kc) {
                    f4 xv = xv4[kc];
                    f4 w0 = xr0[kc], w1 = xr1[kc], w2 = xr2[kc], w3 = xr3[kc];
                    const h2* xpv = (const h2*)&xv;
                    const h2* p0 = (const h2*)&w0;
                    const h2* p1 = (const h2*)&w1;
                    const h2* p2 = (const h2*)&w2;
                    const h2* p3 = (const h2*)&w3;
#pragma unroll
                    for (int u = 0; u < 4; ++u) {
                        a0 = __builtin_amdgcn_fdot2(p0[u], xpv[u], a0, false);
                        a1 = __builtin_amdgcn_fdot2(p1[u], xpv[u], a1, false);
                        a2 = __builtin_amdgcn_fdot2(p2[u], xpv[u], a2, false);
                        a3 = __builtin_amdgcn_fdot2(p3[u], xpv[u], a3, false);
                    }
                }
            }
        }
        {
            const f4* hx4 = (const f4*)hx_h2;  // 64 x f4 (256 h2)
            const f4* r0 = w1r;
            const f4* r1 = w1r + 64;
            const f4* r2 = w1r + 128;
            const f4* r3 = w1r + 192;
#pragma unroll 4
            for (int kc = 0; kc < 64; ++kc) {
                f4 hv = hx4[kc];
                f4 w0 = r0[kc], w1 = r1[kc], w2 = r2[kc], w3 = r3[kc];
                const h2* hp = (const h2*)&hv;
                const h2* p0 = (const h2*)&w0;
                const h2* p1 = (const h2*)&w1;
                const h2* p2 = (const h2*)&w2;
                const h2* p3 = (const h2*)&w3;
#pragma unroll
                for (int u = 0; u < 4; ++u) {
                    a0 = __builtin_amdgcn_fdot2(p0[u], hp[u], a0, false);
                    a1 = __builtin_amdgcn_fdot2(p1[u], hp[u], a1, false);
                    a2 = __builtin_amdgcn_fdot2(p2[u], hp[u], a2, false);
                    a3 = __builtin_amdgcn_fdot2(p3[u], hp[u], a3, false);
                }
            }
        }
        g_ld[j0] = a0; g_ld[j0 + 1] = a1; g_ld[j0 + 2] = a2; g_ld[j0 + 3] = a3;
        __syncthreads();

        // ---- elementwise A: mod_x pack + f/o gates ----
        if (tid < 128) {
            float m0 = sigf(g_ld[2048 + 2 * tid]);
            float m1 = sigf(g_ld[2048 + 2 * tid + 1]);
            h2 p;
            p[0] = (_Float16)(m0 * x_ld[2 * tid]);
            p[1] = (_Float16)(m1 * x_ld[2 * tid + 1]);
            modx_h2[tid] = p;
        } else if (tid < 640) {
            int u = tid - 128;
            float fs = sigf(g_ld[u]);
            float fl = sigf(g_ld[512 + u]);
            float al = sigf(g_ld[1024 + u]);
            f_ld[u] = al * fs + (1.0f - al) * fl;
            o_ld[u] = sigf(g_ld[1536 + u]);
        }
        __syncthreads();

        // ---- GEMM2 (mod_x @ W_C_x) + state update + output ----
        if (tid < 512) {
            float s = g_ld[2304 + tid];  // h-part of W_C + b_C
            const f4* w2r = (const f4*)(W2t + (size_t)tid * 256);
            const f4* mx4 = (const f4*)modx_h2;  // 32 x f4
#pragma unroll 4
            for (int kc = 0; kc < 32; ++kc) {
                f4 wv = w2r[kc];
                f4 mv = mx4[kc];
                const h2* wp = (const h2*)&wv;
                const h2* mp = (const h2*)&mv;
#pragma unroll
                for (int u = 0; u < 4; ++u)
                    s = __builtin_amdgcn_fdot2(wp[u], mp[u], s, false);
            }
            float ch = tanhf(s);
            float f  = f_ld[tid];
            float c  = f * c_ld[tid] + (1.0f - f) * ch;
            c_ld[tid] = c;
            float h  = o_ld[tid] * tanhf(c);
            h_ld[tid] = h;
            orow[t * UU + tid] = h;
        }
        __syncthreads();
    }
}

// =====================================================================
extern "C" void kernel_launch(void* const* d_in, const int* in_sizes, int n_in,
                              void* d_out, int out_size, void* d_ws, size_t ws_size,
                              hipStream_t stream)
{
    (void)in_sizes; (void)n_in; (void)out_size;
    const float* x   = (const float*)d_in[0];
    const float* h0  = (const float*)d_in[1];
    const float* c0  = (const float*)d_in[2];
    const float* Wfs = (const float*)d_in[3];
    const float* bfs = (const float*)d_in[4];
    const float* Wfl = (const float*)d_in[5];
    const float* bfl = (const float*)d_in[6];
    const float* Wal = (const float*)d_in[7];
    const float* bal = (const float*)d_in[8];
    const float* Wm  = (const float*)d_in[9];
    const float* bm  = (const float*)d_in[10];
    const float* WC  = (const float*)d_in[11];
    const float* bC  = (const float*)d_in[12];
    const float* Wo  = (const float*)d_in[13];
    const float* bo  = (const float*)d_in[14];

    char* ws = (char*)d_ws;
    _Float16* W1t  = (_Float16*)(ws + OFF_W1T);
    _Float16* W2t  = (_Float16*)(ws + OFF_W2T);
    _Float16* WxT  = (_Float16*)(ws + OFF_WXT);
    float*    b1   = (float*)   (ws + OFF_B1);
    _Float16* Xpre = (_Float16*)(ws + OFF_XPRE);

    repack_kernel<<<dim3(1024), dim3(256), 0, stream>>>(
        Wfs, Wfl, Wal, Wm, WC, Wo, bfs, bfl, bal, bm, bC, bo,
        W1t, W2t, WxT, b1);

    if (ws_size >= WS_FULL) {
        xpre_kernel<<<dim3(256, 18), dim3(256), 0, stream>>>(x, WxT, Xpre);
        rnn_kernel<true><<<dim3(BB), dim3(704), 0, stream>>>(
            x, h0, c0, W1t, W2t, WxT, b1, Xpre, (float*)d_out);
    } else {
        rnn_kernel<false><<<dim3(BB), dim3(704), 0, stream>>>(
            x, h0, c0, W1t, W2t, WxT, b1, nullptr, (float*)d_out);
    }
}

// Round 3
// 9757.854 us; speedup vs baseline: 4.6747x; 4.6747x over previous
//
#include <hip/hip_runtime.h>
#include <hip/hip_fp16.h>
#include <math.h>

typedef _Float16 h2 __attribute__((ext_vector_type(2)));
typedef _Float16 h8 __attribute__((ext_vector_type(8)));
typedef float    f4 __attribute__((ext_vector_type(4)));
typedef unsigned int       u32;
typedef unsigned long long u64;

#define BB 64
#define TT 512
#define DD 256
#define UU 512

#define NBLK 64
#define CPB  44   // packed gate-cols per block: 8*{fs,fl,al,o,WCh} + 4 m
#define XPB  36   // of those, cols with an x-contribution (32 gate + 4 m)
#define UPB  8    // h/c columns owned per block
#define MPB  4    // m (x-dim) columns owned per block
#define NJ   2816 // NBLK*CPB
#define NJX  2304 // NBLK*XPB

// ---------- ws layout (bytes) ----------
#define OFF_W1   0ull                              // f16 [2816][512] packed, K-contig
#define OFF_W2   (OFF_W1 + 2816ull*512*2)          // f16 [512][256]
#define OFF_WX   (OFF_W2 + 512ull*256*2)           // f16 [2304][256] packed
#define OFF_B1   (OFF_WX + 2304ull*256*2)          // f32 [2816] packed
#define OFF_HB   (OFF_B1 + 2816ull*4)              // f16 [64][512]  h state
#define OFF_MX   (OFF_HB + 64ull*512*2)            // f16 [64][256]  mod_x
#define OFF_CTR  (OFF_MX + 64ull*256*2)            // u32 [1088] barrier counters
#define OFF_XPRE (OFF_CTR + 1088ull*4)             // f16 [512][2304][64]
#define WS_FULL  (OFF_XPRE + 512ull*2304*64*2)     // ~155.4 MB

__device__ __forceinline__ float sigf(float v)     { return 1.0f / (1.0f + __expf(-v)); }
__device__ __forceinline__ float tanhfast(float v) { return 1.0f - 2.0f / (__expf(2.0f * v) + 1.0f); }

// grid barrier: per-instance counter (never reused -> no reset race).
// __syncthreads drains each wave's vmcnt before s_barrier (compiler-guaranteed),
// so all agent-scope (write-through) stores are LLC-visible before arrival.
__device__ __forceinline__ void gridbar(u32* c, int tid) {
    __syncthreads();
    if (tid == 0) {
        __hip_atomic_fetch_add(c, 1u, __ATOMIC_ACQ_REL, __HIP_MEMORY_SCOPE_AGENT);
        u32 it = 0;
        while (__hip_atomic_load(c, __ATOMIC_ACQUIRE, __HIP_MEMORY_SCOPE_AGENT) < (u32)NBLK) {
            __builtin_amdgcn_s_sleep(2);
            if (++it > 2000000u) break;   // safety valve (never triggers when co-resident)
        }
    }
    __syncthreads();
}

// packed-order helpers (fallback path)
__device__ __forceinline__ int pk5(int g, int u) { return (u >> 3) * 44 + g * 8 + (u & 7); }
__device__ __forceinline__ int pkm(int d)        { return (d >> 2) * 44 + 40 + (d & 3); }

// =====================================================================
// Kernel 1: repack weights into packed block-sliced f16 layouts + zero ctrs
// packed col J = blk*44 + c; c: 0-7 fs(u), 8-15 fl, 16-23 al, 24-31 o,
// 32-39 WC_h, 40-43 m.  x-col Jx = blk*36 + lc; lc: 0-31 gates, 32-35 m.
// =====================================================================
__global__ void repack_kernel(const float* __restrict__ Wfs, const float* __restrict__ Wfl,
                              const float* __restrict__ Wal, const float* __restrict__ Wm,
                              const float* __restrict__ WC,  const float* __restrict__ Wo,
                              const float* __restrict__ bfs, const float* __restrict__ bfl,
                              const float* __restrict__ bal, const float* __restrict__ bm,
                              const float* __restrict__ bC,  const float* __restrict__ bo,
                              _Float16* __restrict__ W1, _Float16* __restrict__ W2,
                              _Float16* __restrict__ WxT, float* __restrict__ b1,
                              u32* __restrict__ ctr)
{
    const int stride = gridDim.x * blockDim.x;
    const int idx = blockIdx.x * blockDim.x + threadIdx.x;

    for (int i = idx; i < 2816 * 512; i += stride) {
        int J = i >> 9, k = i & 511;
        int blk = J / 44, c = J - blk * 44;
        float v;
        if (c < 40) {
            int grp = c >> 3, u = blk * 8 + (c & 7);
            const float* Wg = (grp == 0) ? Wfs : (grp == 1) ? Wfl : (grp == 2) ? Wal : (grp == 3) ? Wo : WC;
            v = Wg[(size_t)k * 512 + u];
        } else {
            int d = blk * 4 + (c - 40);
            v = Wm[(size_t)k * 256 + d];
        }
        W1[i] = (_Float16)v;
    }
    for (int i = idx; i < 512 * 256; i += stride) {
        int u = i >> 8, dd = i & 255;
        W2[i] = (_Float16)WC[(size_t)(512 + dd) * 512 + u];
    }
    for (int i = idx; i < 2304 * 256; i += stride) {
        int Jx = i >> 8, k2 = i & 255;
        int blk = Jx / 36, lc = Jx - blk * 36;
        float v;
        if (lc < 32) {
            int grp = lc >> 3, u = blk * 8 + (lc & 7);
            const float* Wg = (grp == 0) ? Wfs : (grp == 1) ? Wfl : (grp == 2) ? Wal : Wo;
            v = Wg[(size_t)(512 + k2) * 512 + u];
        } else {
            int d = blk * 4 + (lc - 32);
            v = Wm[(size_t)(512 + k2) * 256 + d];
        }
        WxT[i] = (_Float16)v;
    }
    for (int J = idx; J < 2816; J += stride) {
        int blk = J / 44, c = J - blk * 44;
        float v;
        if (c < 40) {
            int grp = c >> 3, u = blk * 8 + (c & 7);
            v = (grp == 0) ? bfs[u] : (grp == 1) ? bfl[u] : (grp == 2) ? bal[u] : (grp == 3) ? bo[u] : bC[u];
        } else {
            v = bm[blk * 4 + (c - 40)];
        }
        b1[J] = v;
    }
    for (int i = idx; i < 1088; i += stride) ctr[i] = 0;
}

// =====================================================================
// Kernel 2: Xpre = x @ W_x via MFMA.  [32768,256]@[256,2304] -> f16
// output layout [t][Jx][b] for coalesced in-loop reads.
// =====================================================================
__global__ __launch_bounds__(256) void xpre_kernel(const float* __restrict__ x,
                                                   const _Float16* __restrict__ WxT,
                                                   _Float16* __restrict__ Xpre)
{
    __shared__ _Float16 As[128 * 32];
    __shared__ _Float16 Bs[128 * 32];

    const int tid  = threadIdx.x;
    const int lane = tid & 63;
    const int w    = tid >> 6;
    const int wm   = w >> 1, wn = w & 1;
    const int quad = lane >> 4, l16 = lane & 15;
    const int row0 = blockIdx.x * 128;
    const int n0   = blockIdx.y * 128;

    f4 acc[4][4];
    for (int i = 0; i < 4; ++i)
        for (int j = 0; j < 4; ++j)
            acc[i][j] = (f4){0.f, 0.f, 0.f, 0.f};

    for (int kt = 0; kt < 8; ++kt) {
        const int k0 = kt * 32;
        {
            int r  = tid >> 3;
            int cg = (tid & 7) * 4;
            for (int rr = r; rr < 128; rr += 32) {
                f4 v = *(const f4*)&x[(size_t)(row0 + rr) * 256 + k0 + cg];
                As[rr * 32 + cg + 0] = (_Float16)v.x;
                As[rr * 32 + cg + 1] = (_Float16)v.y;
                As[rr * 32 + cg + 2] = (_Float16)v.z;
                As[rr * 32 + cg + 3] = (_Float16)v.w;
            }
        }
        {
            int r   = tid & 127;
            int seg = (tid >> 7) * 16;
            const _Float16* src = &WxT[(size_t)(n0 + r) * 256 + k0 + seg];
            *(f4*)&Bs[r * 32 + seg]     = *(const f4*)src;
            *(f4*)&Bs[r * 32 + seg + 8] = *(const f4*)(src + 8);
        }
        __syncthreads();

        h8 af[4], bf[4];
#pragma unroll
        for (int f = 0; f < 4; ++f) {
            af[f] = *(const h8*)&As[(wm * 64 + f * 16 + l16) * 32 + quad * 8];
            bf[f] = *(const h8*)&Bs[(wn * 64 + f * 16 + l16) * 32 + quad * 8];
        }
#pragma unroll
        for (int fm = 0; fm < 4; ++fm)
#pragma unroll
            for (int fn = 0; fn < 4; ++fn)
                acc[fm][fn] = __builtin_amdgcn_mfma_f32_16x16x32_f16(af[fm], bf[fn], acc[fm][fn], 0, 0, 0);
        __syncthreads();
    }

#pragma unroll
    for (int fm = 0; fm < 4; ++fm)
#pragma unroll
        for (int fn = 0; fn < 4; ++fn)
#pragma unroll
            for (int r = 0; r < 4; ++r) {
                int rr = row0 + wm * 64 + fm * 16 + quad * 4 + r;  // x row = b*T+t
                int J  = n0 + wn * 64 + fn * 16 + l16;
                int b = rr >> 9, tt = rr & 511;
                Xpre[((size_t)tt * NJX + J) * 64 + b] = (_Float16)acc[fm][fn][r];
            }
}

// =====================================================================
// Kernel 3: cooperative recurrent scan. 64 blocks x 256 thr, weights
// LDS-resident; per step: MFMA gate GEMM -> barrier -> MFMA GEMM2 +
// state update -> barrier.
// =====================================================================
__global__ __launch_bounds__(256, 1) void rnn_coop(
    const float* __restrict__ x, const float* __restrict__ h0, const float* __restrict__ c0,
    const _Float16* __restrict__ W1, const _Float16* __restrict__ W2,
    const float* __restrict__ b1, const _Float16* __restrict__ Xpre,
    _Float16* __restrict__ hbuf, _Float16* __restrict__ mxbuf, u32* __restrict__ ctr,
    float* __restrict__ out)
{
    __shared__ __align__(16) _Float16 sW1[48 * 512];  // 49 KB, resident all steps
    __shared__ __align__(16) _Float16 sW2[16 * 256];  // 8 KB
    __shared__ __align__(16) _Float16 sHM[64 * 512];  // phase A: h; phase B: modx
    __shared__ float sS[48 * 64];
    __shared__ float sF[8 * 64];
    __shared__ float sO[8 * 64];
    __shared__ float sCP[8 * 64];
    __shared__ float sC[8 * 64];
    __shared__ float sB1[44];

    const int tid  = threadIdx.x;
    const int blk  = blockIdx.x;
    const int lane = tid & 63;
    const int w    = tid >> 6;
    const int l16  = lane & 15;
    const int quad = lane >> 4;
    const int swz  = l16 & 7;   // shared frag-row swizzle (rows ≡ l16 mod 8 everywhere)

    // ---- stage W1 slice (44 rows + 4 zero-pad) with chunk swizzle ----
    for (int idx = tid; idx < 48 * 64; idx += 256) {
        int r = idx >> 6, j = idx & 63;
        h8 v = {};
        if (r < CPB) v = *(const h8*)(W1 + ((size_t)(blk * CPB + r) * 512 + j * 8));
        *(h8*)&sW1[(r * 64 + (j ^ (r & 7))) * 8] = v;
    }
    // ---- stage W2 slice (8 rows + 8 zero-pad) ----
    for (int idx = tid; idx < 16 * 32; idx += 256) {
        int r = idx >> 5, j = idx & 31;
        h8 v = {};
        if (r < UPB) v = *(const h8*)(W2 + ((size_t)(blk * UPB + r) * 256 + j * 8));
        *(h8*)&sW2[(r * 32 + (j ^ (r & 7))) * 8] = v;
    }
    if (tid < CPB) sB1[tid] = b1[blk * CPB + tid];
    // ---- init c (block-local) and our h slice (global, agent-visible) ----
    for (int idx = tid; idx < UPB * 64; idx += 256) {
        int u = idx >> 6, b = idx & 63;
        sC[u * 64 + b] = c0[b * UU + blk * UPB + u];
        _Float16 hf = (_Float16)h0[b * UU + blk * UPB + u];
        unsigned short hv; __builtin_memcpy(&hv, &hf, 2);
        __hip_atomic_store((unsigned short*)hbuf + (size_t)b * 512 + blk * UPB + u, hv,
                           __ATOMIC_RELAXED, __HIP_MEMORY_SCOPE_AGENT);
    }
    gridbar(&ctr[1024], tid);

    for (int t = 0; t < TT; ++t) {
        // ---- stage h [64][512] -> sHM (swizzled 16B chunks) ----
        for (int idx = tid; idx < 64 * 64; idx += 256) {
            int r = idx >> 6, j = idx & 63;
            u64* src = (u64*)(hbuf + (size_t)r * 512 + j * 8);
            u64 lo = __hip_atomic_load(src,     __ATOMIC_RELAXED, __HIP_MEMORY_SCOPE_AGENT);
            u64 hi = __hip_atomic_load(src + 1, __ATOMIC_RELAXED, __HIP_MEMORY_SCOPE_AGENT);
            u64* dst = (u64*)&sHM[(r * 64 + (j ^ (r & 7))) * 8];
            dst[0] = lo; dst[1] = hi;
        }
        __syncthreads();

        // ---- GEMM1: S[c][b] = Wslice[c][k] * h[b][k] ----
        f4 acc0 = {0.f,0.f,0.f,0.f}, acc1 = {0.f,0.f,0.f,0.f}, acc2 = {0.f,0.f,0.f,0.f};
        {
            const int br = w * 16 + l16;  // B-row (batch)
#pragma unroll
            for (int ks = 0; ks < 16; ++ks) {
                int j  = ks * 4 + quad;
                int jx = j ^ swz;
                h8 bf = *(const h8*)&sHM[(br * 64 + jx) * 8];
                h8 a0 = *(const h8*)&sW1[((     l16) * 64 + jx) * 8];
                h8 a1 = *(const h8*)&sW1[((16 + l16) * 64 + jx) * 8];
                h8 a2 = *(const h8*)&sW1[((32 + l16) * 64 + jx) * 8];
                acc0 = __builtin_amdgcn_mfma_f32_16x16x32_f16(a0, bf, acc0, 0, 0, 0);
                acc1 = __builtin_amdgcn_mfma_f32_16x16x32_f16(a1, bf, acc1, 0, 0, 0);
                acc2 = __builtin_amdgcn_mfma_f32_16x16x32_f16(a2, bf, acc2, 0, 0, 0);
            }
        }
        {
            int col = w * 16 + l16;
#pragma unroll
            for (int r = 0; r < 4; ++r) {
                sS[(     quad * 4 + r) * 64 + col] = acc0[r];
                sS[(16 + quad * 4 + r) * 64 + col] = acc1[r];
                sS[(32 + quad * 4 + r) * 64 + col] = acc2[r];
            }
        }
        __syncthreads();

        // ---- elementwise: gates, f/o, cpre, mod_x ----
        {
            const _Float16* xp = Xpre + ((size_t)t * NJX + blk * XPB) * 64;
            int b = lane;
#pragma unroll
            for (int i = 0; i < 2; ++i) {
                int u = w * 2 + i;
                float fs = sS[u * 64 + b]        + sB1[u]      + (float)xp[(size_t)u * 64 + b];
                float fl = sS[(8 + u) * 64 + b]  + sB1[8 + u]  + (float)xp[(size_t)(8 + u) * 64 + b];
                float al = sS[(16 + u) * 64 + b] + sB1[16 + u] + (float)xp[(size_t)(16 + u) * 64 + b];
                float ov = sS[(24 + u) * 64 + b] + sB1[24 + u] + (float)xp[(size_t)(24 + u) * 64 + b];
                fs = sigf(fs); fl = sigf(fl); al = sigf(al);
                sF[u * 64 + b]  = al * fs + (1.0f - al) * fl;
                sO[u * 64 + b]  = sigf(ov);
                sCP[u * 64 + b] = sS[(32 + u) * 64 + b] + sB1[32 + u];
            }
            {
                int d = w;  // 0..3
                float mr = sS[(40 + d) * 64 + b] + sB1[40 + d] + (float)xp[(size_t)(32 + d) * 64 + b];
                float xv = x[((size_t)b * TT + t) * DD + blk * MPB + d];
                _Float16 mv = (_Float16)(sigf(mr) * xv);
                unsigned short mu; __builtin_memcpy(&mu, &mv, 2);
                __hip_atomic_store((unsigned short*)mxbuf + (size_t)b * 256 + blk * MPB + d, mu,
                                   __ATOMIC_RELAXED, __HIP_MEMORY_SCOPE_AGENT);
            }
        }
        gridbar(&ctr[2 * t], tid);

        // ---- stage mod_x [64][256] -> sHM (h is dead) ----
        for (int idx = tid; idx < 64 * 32; idx += 256) {
            int r = idx >> 5, j = idx & 31;
            u64* src = (u64*)(mxbuf + (size_t)r * 256 + j * 8);
            u64 lo = __hip_atomic_load(src,     __ATOMIC_RELAXED, __HIP_MEMORY_SCOPE_AGENT);
            u64 hi = __hip_atomic_load(src + 1, __ATOMIC_RELAXED, __HIP_MEMORY_SCOPE_AGENT);
            u64* dst = (u64*)&sHM[(r * 32 + (j ^ (r & 7))) * 8];
            dst[0] = lo; dst[1] = hi;
        }
        __syncthreads();

        // ---- GEMM2: chat_pre[u][b] = W2slice[u][d] * modx[b][d]; update ----
        {
            f4 acc = {0.f,0.f,0.f,0.f};
            const int br = w * 16 + l16;
#pragma unroll
            for (int ks = 0; ks < 8; ++ks) {
                int j  = ks * 4 + quad;
                int jx = j ^ swz;
                h8 bf = *(const h8*)&sHM[(br * 32 + jx) * 8];
                h8 af = *(const h8*)&sW2[(l16 * 32 + jx) * 8];
                acc = __builtin_amdgcn_mfma_f32_16x16x32_f16(af, bf, acc, 0, 0, 0);
            }
            if (quad < 2) {
                int b  = w * 16 + l16;
                int u0 = quad * 4;
                float hv[4];
#pragma unroll
                for (int r = 0; r < 4; ++r) {
                    int u = u0 + r;
                    float ch = tanhfast(acc[r] + sCP[u * 64 + b]);
                    float f  = sF[u * 64 + b];
                    float c  = f * sC[u * 64 + b] + (1.0f - f) * ch;
                    sC[u * 64 + b] = c;
                    hv[r] = sO[u * 64 + b] * tanhfast(c);
                }
                _Float16 hp[4] = {(_Float16)hv[0], (_Float16)hv[1], (_Float16)hv[2], (_Float16)hv[3]};
                u64 hq; __builtin_memcpy(&hq, hp, 8);
                __hip_atomic_store((u64*)(hbuf + (size_t)b * 512 + blk * UPB + u0), hq,
                                   __ATOMIC_RELAXED, __HIP_MEMORY_SCOPE_AGENT);
                f4 ovec = {hv[0], hv[1], hv[2], hv[3]};
                *(f4*)&out[((size_t)b * TT + t) * UU + blk * UPB + u0] = ovec;
            }
        }
        gridbar(&ctr[2 * t + 1], tid);
    }
}

// =====================================================================
// Fallback (small ws): round-2-style per-batch dot2 scan on packed weights.
// =====================================================================
__global__ __launch_bounds__(704) void rnn_fb(const float* __restrict__ x,
                                              const float* __restrict__ h0,
                                              const float* __restrict__ c0,
                                              const _Float16* __restrict__ W1,
                                              const _Float16* __restrict__ W2,
                                              const _Float16* __restrict__ WxT,
                                              const float* __restrict__ b1g,
                                              float* __restrict__ out)
{
    __shared__ float g_ld[2816];
    __shared__ float b1_ld[2816];
    __shared__ float h_ld[512];
    __shared__ float x_ld[256];
    __shared__ float f_ld[512];
    __shared__ float o_ld[512];
    __shared__ float c_ld[512];
    __shared__ __align__(16) h2 hx_h2[256];
    __shared__ __align__(16) h2 x16_h2[128];
    __shared__ __align__(16) h2 modx_h2[128];

    const int tid = threadIdx.x;
    const int b   = blockIdx.x;
    const int j0  = tid * 4;
    const int c   = j0 % 44;
    const bool hasx = (c < 32) || (c >= 40);
    const int Jx0 = (j0 / 44) * 36 + (c < 32 ? c : c - 8);

    for (int j = tid; j < 2816; j += 704) b1_ld[j] = b1g[j];
    if (tid < 512) {
        h_ld[tid] = h0[b * 512 + tid];
        c_ld[tid] = c0[b * 512 + tid];
    }
    __syncthreads();

    const f4* __restrict__ w1r = (const f4*)(W1 + (size_t)j0 * 512);
    const float* __restrict__ xrow = x + (size_t)b * TT * DD;
    float* __restrict__ orow = out + (size_t)b * TT * UU;

    for (int t = 0; t < TT; ++t) {
        if (tid < 256) {
            h2 p; p[0] = (_Float16)h_ld[2 * tid]; p[1] = (_Float16)h_ld[2 * tid + 1];
            hx_h2[tid] = p;
        } else if (tid < 384) {
            int i = tid - 256;
            float v0 = xrow[t * DD + 2 * i];
            float v1 = xrow[t * DD + 2 * i + 1];
            x_ld[2 * i] = v0; x_ld[2 * i + 1] = v1;
            h2 p; p[0] = (_Float16)v0; p[1] = (_Float16)v1;
            x16_h2[i] = p;
        }
        __syncthreads();

        float a0 = b1_ld[j0], a1 = b1_ld[j0 + 1], a2 = b1_ld[j0 + 2], a3 = b1_ld[j0 + 3];
        if (hasx) {
            const f4* xr0 = (const f4*)(WxT + (size_t)Jx0 * 256);
            const f4* xr1 = xr0 + 32;
            const f4* xr2 = xr0 + 64;
            const f4* xr3 = xr0 + 96;
            const f4* xv4 = (const f4*)x16_h2;
#pragma unroll 4
            for (int kc = 0; kc < 32; ++kc) {
                f4 xv = xv4[kc];
                f4 w0 = xr0[kc], w1 = xr1[kc], w2 = xr2[kc], w3 = xr3[kc];
                const h2* xpv = (const h2*)&xv;
                const h2* p0 = (const h2*)&w0; const h2* p1 = (const h2*)&w1;
                const h2* p2 = (const h2*)&w2; const h2* p3 = (const h2*)&w3;
#pragma unroll
                for (int u = 0; u < 4; ++u) {
                    a0 = __builtin_amdgcn_fdot2(p0[u], xpv[u], a0, false);
                    a1 = __builtin_amdgcn_fdot2(p1[u], xpv[u], a1, false);
                    a2 = __builtin_amdgcn_fdot2(p2[u], xpv[u], a2, false);
                    a3 = __builtin_amdgcn_fdot2(p3[u], xpv[u], a3, false);
                }
            }
        }
        {
            const f4* hx4 = (const f4*)hx_h2;
            const f4* r0 = w1r;
            const f4* r1 = w1r + 64;
            const f4* r2 = w1r + 128;
            const f4* r3 = w1r + 192;
#pragma unroll 4
            for (int kc = 0; kc < 64; ++kc) {
                f4 hv = hx4[kc];
                f4 w0 = r0[kc], w1 = r1[kc], w2 = r2[kc], w3 = r3[kc];
                const h2* hp = (const h2*)&hv;
                const h2* p0 = (const h2*)&w0; const h2* p1 = (const h2*)&w1;
                const h2* p2 = (const h2*)&w2; const h2* p3 = (const h2*)&w3;
#pragma unroll
                for (int u = 0; u < 4; ++u) {
                    a0 = __builtin_amdgcn_fdot2(p0[u], hp[u], a0, false);
                    a1 = __builtin_amdgcn_fdot2(p1[u], hp[u], a1, false);
                    a2 = __builtin_amdgcn_fdot2(p2[u], hp[u], a2, false);
                    a3 = __builtin_amdgcn_fdot2(p3[u], hp[u], a3, false);
                }
            }
        }
        g_ld[j0] = a0; g_ld[j0 + 1] = a1; g_ld[j0 + 2] = a2; g_ld[j0 + 3] = a3;
        __syncthreads();

        if (tid < 128) {
            float m0 = sigf(g_ld[pkm(2 * tid)]);
            float m1 = sigf(g_ld[pkm(2 * tid + 1)]);
            h2 p;
            p[0] = (_Float16)(m0 * x_ld[2 * tid]);
            p[1] = (_Float16)(m1 * x_ld[2 * tid + 1]);
            modx_h2[tid] = p;
        } else if (tid < 640) {
            int u = tid - 128;
            float fs = sigf(g_ld[pk5(0, u)]);
            float fl = sigf(g_ld[pk5(1, u)]);
            float al = sigf(g_ld[pk5(2, u)]);
            f_ld[u] = al * fs + (1.0f - al) * fl;
            o_ld[u] = sigf(g_ld[pk5(3, u)]);
        }
        __syncthreads();

        if (tid < 512) {
            float s = g_ld[pk5(4, tid)];
            const f4* w2r = (const f4*)(W2 + (size_t)tid * 256);
            const f4* mx4 = (const f4*)modx_h2;
#pragma unroll 4
            for (int kc = 0; kc < 32; ++kc) {
                f4 wv = w2r[kc];
                f4 mv = mx4[kc];
                const h2* wp = (const h2*)&wv;
                const h2* mp = (const h2*)&mv;
#pragma unroll
                for (int u = 0; u < 4; ++u)
                    s = __builtin_amdgcn_fdot2(wp[u], mp[u], s, false);
            }
            float ch = tanhfast(s);
            float f  = f_ld[tid];
            float cc = f * c_ld[tid] + (1.0f - f) * ch;
            c_ld[tid] = cc;
            float h  = o_ld[tid] * tanhfast(cc);
            h_ld[tid] = h;
            orow[t * UU + tid] = h;
        }
        __syncthreads();
    }
}

// =====================================================================
extern "C" void kernel_launch(void* const* d_in, const int* in_sizes, int n_in,
                              void* d_out, int out_size, void* d_ws, size_t ws_size,
                              hipStream_t stream)
{
    (void)in_sizes; (void)n_in; (void)out_size;
    const float* x   = (const float*)d_in[0];
    const float* h0  = (const float*)d_in[1];
    const float* c0  = (const float*)d_in[2];
    const float* Wfs = (const float*)d_in[3];
    const float* bfs = (const float*)d_in[4];
    const float* Wfl = (const float*)d_in[5];
    const float* bfl = (const float*)d_in[6];
    const float* Wal = (const float*)d_in[7];
    const float* bal = (const float*)d_in[8];
    const float* Wm  = (const float*)d_in[9];
    const float* bm  = (const float*)d_in[10];
    const float* WC  = (const float*)d_in[11];
    const float* bC  = (const float*)d_in[12];
    const float* Wo  = (const float*)d_in[13];
    const float* bo  = (const float*)d_in[14];

    char* ws = (char*)d_ws;
    _Float16* W1   = (_Float16*)(ws + OFF_W1);
    _Float16* W2   = (_Float16*)(ws + OFF_W2);
    _Float16* WxT  = (_Float16*)(ws + OFF_WX);
    float*    b1   = (float*)   (ws + OFF_B1);
    _Float16* hbuf = (_Float16*)(ws + OFF_HB);
    _Float16* mxbf = (_Float16*)(ws + OFF_MX);
    u32*      ctr  = (u32*)     (ws + OFF_CTR);
    _Float16* Xpre = (_Float16*)(ws + OFF_XPRE);

    repack_kernel<<<dim3(1024), dim3(256), 0, stream>>>(
        Wfs, Wfl, Wal, Wm, WC, Wo, bfs, bfl, bal, bm, bC, bo, W1, W2, WxT, b1, ctr);

    if (ws_size >= WS_FULL) {
        xpre_kernel<<<dim3(256, 18), dim3(256), 0, stream>>>(x, WxT, Xpre);
        rnn_coop<<<dim3(NBLK), dim3(256), 0, stream>>>(
            x, h0, c0, W1, W2, b1, Xpre, hbuf, mxbf, ctr, (float*)d_out);
    } else {
        rnn_fb<<<dim3(BB), dim3(704), 0, stream>>>(
            x, h0, c0, W1, W2, WxT, b1, (float*)d_out);
    }
}

// Round 4
// 9273.476 us; speedup vs baseline: 4.9189x; 1.0522x over previous
//
#include <hip/hip_runtime.h>
#include <hip/hip_fp16.h>
#include <math.h>

typedef _Float16 h2 __attribute__((ext_vector_type(2)));
typedef _Float16 h8 __attribute__((ext_vector_type(8)));
typedef float    f4 __attribute__((ext_vector_type(4)));
typedef unsigned int       u32;
typedef unsigned long long u64;

#define BB 64
#define TT 512
#define DD 256
#define UU 512

#define NBLK 64
#define CPB  44   // packed gate-cols per block: 8*{fs,fl,al,o,WCh} + 4 m
#define XPB  36   // of those, cols with an x-contribution (32 gate + 4 m)
#define UPB  8    // h/c columns owned per block
#define MPB  4    // m (x-dim) columns owned per block
#define NJ   2816
#define NJX  2304

// ---------- ws layout (bytes) ----------
#define OFF_W1   0ull                              // f16 [2816][512] packed, K-contig
#define OFF_W2   (OFF_W1 + 2816ull*512*2)          // f16 [512][256]
#define OFF_WX   (OFF_W2 + 512ull*256*2)           // f16 [2304][256] packed
#define OFF_B1   (OFF_WX + 2304ull*256*2)          // f32 [2816] packed
#define OFF_HB   (OFF_B1 + 2816ull*4)              // f16 [64][512]  h state
#define OFF_MX   (OFF_HB + 64ull*512*2)            // f16 [64][256]  mod_x
#define OFF_CTR  (OFF_MX + 64ull*256*2)            // u32 [1025*16] barrier ctrs (1/line)
#define OFF_XPRE (OFF_CTR + 16400ull*4)            // f16 [512][2304][64]
#define WS_FULL  (OFF_XPRE + 512ull*2304*64*2)     // ~155.5 MB

__device__ __forceinline__ float sigf(float v)     { return 1.0f / (1.0f + __expf(-v)); }
__device__ __forceinline__ float tanhfast(float v) { return 1.0f - 2.0f / (__expf(2.0f * v) + 1.0f); }

// grid barrier, __ockl_grid_sync pattern: entry __syncthreads drains every
// wave's vmcnt (plain stores are in L2); leader's ACQ_REL add emits the
// agent-release (buffer_wbl2 sc1 -> exchange data reaches LLC) then the
// acquire poll emits buffer_inv sc1 (invalidate stale L1/L2 lines); exit
// __syncthreads orders the inv before any wave's plain loads.
__device__ __forceinline__ void gridbar(u32* c, int tid) {
    __syncthreads();
    if (tid == 0) {
        __hip_atomic_fetch_add(c, 1u, __ATOMIC_ACQ_REL, __HIP_MEMORY_SCOPE_AGENT);
        u32 it = 0;
        while (__hip_atomic_load(c, __ATOMIC_ACQUIRE, __HIP_MEMORY_SCOPE_AGENT) < (u32)NBLK) {
            __builtin_amdgcn_s_sleep(1);
            if (++it > 4000000u) break;   // safety valve (never triggers when co-resident)
        }
    }
    __syncthreads();
}

// packed-order helpers (fallback path)
__device__ __forceinline__ int pk5(int g, int u) { return (u >> 3) * 44 + g * 8 + (u & 7); }
__device__ __forceinline__ int pkm(int d)        { return (d >> 2) * 44 + 40 + (d & 3); }

// =====================================================================
// Kernel 1: repack weights into packed block-sliced f16 layouts + zero ctrs
// =====================================================================
__global__ void repack_kernel(const float* __restrict__ Wfs, const float* __restrict__ Wfl,
                              const float* __restrict__ Wal, const float* __restrict__ Wm,
                              const float* __restrict__ WC,  const float* __restrict__ Wo,
                              const float* __restrict__ bfs, const float* __restrict__ bfl,
                              const float* __restrict__ bal, const float* __restrict__ bm,
                              const float* __restrict__ bC,  const float* __restrict__ bo,
                              _Float16* __restrict__ W1, _Float16* __restrict__ W2,
                              _Float16* __restrict__ WxT, float* __restrict__ b1,
                              u32* __restrict__ ctr)
{
    const int stride = gridDim.x * blockDim.x;
    const int idx = blockIdx.x * blockDim.x + threadIdx.x;

    for (int i = idx; i < 2816 * 512; i += stride) {
        int J = i >> 9, k = i & 511;
        int blk = J / 44, c = J - blk * 44;
        float v;
        if (c < 40) {
            int grp = c >> 3, u = blk * 8 + (c & 7);
            const float* Wg = (grp == 0) ? Wfs : (grp == 1) ? Wfl : (grp == 2) ? Wal : (grp == 3) ? Wo : WC;
            v = Wg[(size_t)k * 512 + u];
        } else {
            int d = blk * 4 + (c - 40);
            v = Wm[(size_t)k * 256 + d];
        }
        W1[i] = (_Float16)v;
    }
    for (int i = idx; i < 512 * 256; i += stride) {
        int u = i >> 8, dd = i & 255;
        W2[i] = (_Float16)WC[(size_t)(512 + dd) * 512 + u];
    }
    for (int i = idx; i < 2304 * 256; i += stride) {
        int Jx = i >> 8, k2 = i & 255;
        int blk = Jx / 36, lc = Jx - blk * 36;
        float v;
        if (lc < 32) {
            int grp = lc >> 3, u = blk * 8 + (lc & 7);
            const float* Wg = (grp == 0) ? Wfs : (grp == 1) ? Wfl : (grp == 2) ? Wal : Wo;
            v = Wg[(size_t)(512 + k2) * 512 + u];
        } else {
            int d = blk * 4 + (lc - 32);
            v = Wm[(size_t)(512 + k2) * 256 + d];
        }
        WxT[i] = (_Float16)v;
    }
    for (int J = idx; J < 2816; J += stride) {
        int blk = J / 44, c = J - blk * 44;
        float v;
        if (c < 40) {
            int grp = c >> 3, u = blk * 8 + (c & 7);
            v = (grp == 0) ? bfs[u] : (grp == 1) ? bfl[u] : (grp == 2) ? bal[u] : (grp == 3) ? bo[u] : bC[u];
        } else {
            v = bm[blk * 4 + (c - 40)];
        }
        b1[J] = v;
    }
    for (int i = idx; i < 16400; i += stride) ctr[i] = 0;
}

// =====================================================================
// Kernel 2: Xpre = x @ W_x via MFMA.  [32768,256]@[256,2304] -> f16
// output layout [t][Jx][b].
// =====================================================================
__global__ __launch_bounds__(256) void xpre_kernel(const float* __restrict__ x,
                                                   const _Float16* __restrict__ WxT,
                                                   _Float16* __restrict__ Xpre)
{
    __shared__ _Float16 As[128 * 32];
    __shared__ _Float16 Bs[128 * 32];

    const int tid  = threadIdx.x;
    const int lane = tid & 63;
    const int w    = tid >> 6;
    const int wm   = w >> 1, wn = w & 1;
    const int quad = lane >> 4, l16 = lane & 15;
    const int row0 = blockIdx.x * 128;
    const int n0   = blockIdx.y * 128;

    f4 acc[4][4];
    for (int i = 0; i < 4; ++i)
        for (int j = 0; j < 4; ++j)
            acc[i][j] = (f4){0.f, 0.f, 0.f, 0.f};

    for (int kt = 0; kt < 8; ++kt) {
        const int k0 = kt * 32;
        {
            int r  = tid >> 3;
            int cg = (tid & 7) * 4;
            for (int rr = r; rr < 128; rr += 32) {
                f4 v = *(const f4*)&x[(size_t)(row0 + rr) * 256 + k0 + cg];
                As[rr * 32 + cg + 0] = (_Float16)v.x;
                As[rr * 32 + cg + 1] = (_Float16)v.y;
                As[rr * 32 + cg + 2] = (_Float16)v.z;
                As[rr * 32 + cg + 3] = (_Float16)v.w;
            }
        }
        {
            int r   = tid & 127;
            int seg = (tid >> 7) * 16;
            const _Float16* src = &WxT[(size_t)(n0 + r) * 256 + k0 + seg];
            *(f4*)&Bs[r * 32 + seg]     = *(const f4*)src;
            *(f4*)&Bs[r * 32 + seg + 8] = *(const f4*)(src + 8);
        }
        __syncthreads();

        h8 af[4], bf[4];
#pragma unroll
        for (int f = 0; f < 4; ++f) {
            af[f] = *(const h8*)&As[(wm * 64 + f * 16 + l16) * 32 + quad * 8];
            bf[f] = *(const h8*)&Bs[(wn * 64 + f * 16 + l16) * 32 + quad * 8];
        }
#pragma unroll
        for (int fm = 0; fm < 4; ++fm)
#pragma unroll
            for (int fn = 0; fn < 4; ++fn)
                acc[fm][fn] = __builtin_amdgcn_mfma_f32_16x16x32_f16(af[fm], bf[fn], acc[fm][fn], 0, 0, 0);
        __syncthreads();
    }

#pragma unroll
    for (int fm = 0; fm < 4; ++fm)
#pragma unroll
        for (int fn = 0; fn < 4; ++fn)
#pragma unroll
            for (int r = 0; r < 4; ++r) {
                int rr = row0 + wm * 64 + fm * 16 + quad * 4 + r;  // x row = b*T+t
                int J  = n0 + wn * 64 + fn * 16 + l16;
                int b = rr >> 9, tt = rr & 511;
                Xpre[((size_t)tt * NJX + J) * 64 + b] = (_Float16)acc[fm][fn][r];
            }
}

// =====================================================================
// Kernel 3: cooperative recurrent scan. 64 blocks x 256 thr, weights
// LDS-resident. Exchange via PLAIN cached 16B loads/stores; coherence
// from the barrier's agent release/acquire (wbl2/inv).
// =====================================================================
__global__ __launch_bounds__(256, 1) void rnn_coop(
    const float* __restrict__ x, const float* __restrict__ h0, const float* __restrict__ c0,
    const _Float16* __restrict__ W1, const _Float16* __restrict__ W2,
    const float* __restrict__ b1, const _Float16* __restrict__ Xpre,
    _Float16* __restrict__ hbuf, _Float16* __restrict__ mxbuf, u32* __restrict__ ctr,
    float* __restrict__ out)
{
    __shared__ __align__(16) _Float16 sW1[48 * 512];  // 48 KB, resident all steps
    __shared__ __align__(16) _Float16 sW2[16 * 256];  // 8 KB
    __shared__ __align__(16) _Float16 sHM[64 * 512];  // phase A: h; phase B: modx
    __shared__ float sS[48 * 68];                     // stride 68: 2-way max (free)
    __shared__ float sF[8 * 64];
    __shared__ float sO[8 * 64];
    __shared__ float sCP[8 * 64];
    __shared__ float sC[8 * 64];
    __shared__ float sB1[44];

    const int tid  = threadIdx.x;
    const int blk  = blockIdx.x;
    const int lane = tid & 63;
    const int w    = tid >> 6;
    const int l16  = lane & 15;
    const int quad = lane >> 4;
    const int swz  = l16 & 7;

    // ---- stage W1 slice (44 rows + 4 zero-pad) with chunk swizzle ----
    for (int idx = tid; idx < 48 * 64; idx += 256) {
        int r = idx >> 6, j = idx & 63;
        h8 v = {};
        if (r < CPB) v = *(const h8*)(W1 + ((size_t)(blk * CPB + r) * 512 + j * 8));
        *(h8*)&sW1[(r * 64 + (j ^ (r & 7))) * 8] = v;
    }
    // ---- stage W2 slice ----
    for (int idx = tid; idx < 16 * 32; idx += 256) {
        int r = idx >> 5, j = idx & 31;
        h8 v = {};
        if (r < UPB) v = *(const h8*)(W2 + ((size_t)(blk * UPB + r) * 256 + j * 8));
        *(h8*)&sW2[(r * 32 + (j ^ (r & 7))) * 8] = v;
    }
    if (tid < CPB) sB1[tid] = b1[blk * CPB + tid];
    // ---- init c (block-local) and our h slice (plain stores) ----
    for (int idx = tid; idx < UPB * 64; idx += 256) {
        int u = idx >> 6, b = idx & 63;
        sC[u * 64 + b] = c0[b * UU + blk * UPB + u];
        hbuf[(size_t)b * 512 + blk * UPB + u] = (_Float16)h0[b * UU + blk * UPB + u];
    }
    gridbar(&ctr[1024 * 16], tid);

    for (int t = 0; t < TT; ++t) {
        // ---- stage h [64][512] -> sHM (plain 16B cached loads, swizzled) ----
        for (int idx = tid; idx < 64 * 64; idx += 256) {
            int r = idx >> 6, j = idx & 63;
            f4 v = *(const f4*)(hbuf + (size_t)r * 512 + j * 8);
            *(f4*)&sHM[(r * 64 + (j ^ (r & 7))) * 8] = v;
        }
        // ---- prefetch Xpre/x elementwise operands (overlaps h gather) ----
        float pfs[2], pfl[2], pal[2], pov[2], pm, pxv;
        {
            const _Float16* xp = Xpre + ((size_t)t * NJX + blk * XPB) * 64 + lane;
#pragma unroll
            for (int i = 0; i < 2; ++i) {
                int u = w * 2 + i;
                pfs[i] = (float)xp[(size_t)u * 64];
                pfl[i] = (float)xp[(size_t)(8 + u) * 64];
                pal[i] = (float)xp[(size_t)(16 + u) * 64];
                pov[i] = (float)xp[(size_t)(24 + u) * 64];
            }
            pm  = (float)xp[(size_t)(32 + w) * 64];
            pxv = x[((size_t)lane * TT + t) * DD + blk * MPB + w];
        }
        __syncthreads();

        // ---- GEMM1: S[c][b] = Wslice[c][k] * h[b][k] ----
        f4 acc0 = {0.f,0.f,0.f,0.f}, acc1 = {0.f,0.f,0.f,0.f}, acc2 = {0.f,0.f,0.f,0.f};
        {
            const int br = w * 16 + l16;  // B-row (batch)
#pragma unroll
            for (int ks = 0; ks < 16; ++ks) {
                int j  = ks * 4 + quad;
                int jx = j ^ swz;
                h8 bf = *(const h8*)&sHM[(br * 64 + jx) * 8];
                h8 a0 = *(const h8*)&sW1[((     l16) * 64 + jx) * 8];
                h8 a1 = *(const h8*)&sW1[((16 + l16) * 64 + jx) * 8];
                h8 a2 = *(const h8*)&sW1[((32 + l16) * 64 + jx) * 8];
                acc0 = __builtin_amdgcn_mfma_f32_16x16x32_f16(a0, bf, acc0, 0, 0, 0);
                acc1 = __builtin_amdgcn_mfma_f32_16x16x32_f16(a1, bf, acc1, 0, 0, 0);
                acc2 = __builtin_amdgcn_mfma_f32_16x16x32_f16(a2, bf, acc2, 0, 0, 0);
            }
        }
        {
            int col = w * 16 + l16;
#pragma unroll
            for (int r = 0; r < 4; ++r) {
                sS[(     quad * 4 + r) * 68 + col] = acc0[r];
                sS[(16 + quad * 4 + r) * 68 + col] = acc1[r];
                sS[(32 + quad * 4 + r) * 68 + col] = acc2[r];
            }
        }
        __syncthreads();

        // ---- elementwise: gates, f/o, cpre, mod_x ----
        {
            int b = lane;
#pragma unroll
            for (int i = 0; i < 2; ++i) {
                int u = w * 2 + i;
                float fs = sS[u * 68 + b]        + sB1[u]      + pfs[i];
                float fl = sS[(8 + u) * 68 + b]  + sB1[8 + u]  + pfl[i];
                float al = sS[(16 + u) * 68 + b] + sB1[16 + u] + pal[i];
                float ov = sS[(24 + u) * 68 + b] + sB1[24 + u] + pov[i];
                fs = sigf(fs); fl = sigf(fl); al = sigf(al);
                sF[u * 64 + b]  = al * fs + (1.0f - al) * fl;
                sO[u * 64 + b]  = sigf(ov);
                sCP[u * 64 + b] = sS[(32 + u) * 68 + b] + sB1[32 + u];
            }
            {
                int d = w;  // 0..3
                float mr = sS[(40 + d) * 68 + b] + sB1[40 + d] + pm;
                mxbuf[(size_t)b * 256 + blk * MPB + d] = (_Float16)(sigf(mr) * pxv);
            }
        }
        gridbar(&ctr[(2 * t) * 16], tid);

        // ---- stage mod_x [64][256] -> sHM (plain 16B loads) ----
        for (int idx = tid; idx < 64 * 32; idx += 256) {
            int r = idx >> 5, j = idx & 31;
            f4 v = *(const f4*)(mxbuf + (size_t)r * 256 + j * 8);
            *(f4*)&sHM[(r * 32 + (j ^ (r & 7))) * 8] = v;
        }
        __syncthreads();

        // ---- GEMM2: chat_pre[u][b] = W2slice[u][d] * modx[b][d]; update ----
        {
            f4 acc = {0.f,0.f,0.f,0.f};
            const int br = w * 16 + l16;
#pragma unroll
            for (int ks = 0; ks < 8; ++ks) {
                int j  = ks * 4 + quad;
                int jx = j ^ swz;
                h8 bf = *(const h8*)&sHM[(br * 32 + jx) * 8];
                h8 af = *(const h8*)&sW2[(l16 * 32 + jx) * 8];
                acc = __builtin_amdgcn_mfma_f32_16x16x32_f16(af, bf, acc, 0, 0, 0);
            }
            if (quad < 2) {
                int b  = w * 16 + l16;
                int u0 = quad * 4;
                float hv[4];
#pragma unroll
                for (int r = 0; r < 4; ++r) {
                    int u = u0 + r;
                    float ch = tanhfast(acc[r] + sCP[u * 64 + b]);
                    float f  = sF[u * 64 + b];
                    float c  = f * sC[u * 64 + b] + (1.0f - f) * ch;
                    sC[u * 64 + b] = c;
                    hv[r] = sO[u * 64 + b] * tanhfast(c);
                }
                _Float16 hp[4] = {(_Float16)hv[0], (_Float16)hv[1], (_Float16)hv[2], (_Float16)hv[3]};
                u64 hq; __builtin_memcpy(&hq, hp, 8);
                *(u64*)(hbuf + (size_t)b * 512 + blk * UPB + u0) = hq;   // plain store
                f4 ovec = {hv[0], hv[1], hv[2], hv[3]};
                __builtin_nontemporal_store(ovec, (f4*)&out[((size_t)b * TT + t) * UU + blk * UPB + u0]);
            }
        }
        gridbar(&ctr[(2 * t + 1) * 16], tid);
    }
}

// =====================================================================
// Fallback (small ws): per-batch dot2 scan on packed weights.
// =====================================================================
__global__ __launch_bounds__(704) void rnn_fb(const float* __restrict__ x,
                                              const float* __restrict__ h0,
                                              const float* __restrict__ c0,
                                              const _Float16* __restrict__ W1,
                                              const _Float16* __restrict__ W2,
                                              const _Float16* __restrict__ WxT,
                                              const float* __restrict__ b1g,
                                              float* __restrict__ out)
{
    __shared__ float g_ld[2816];
    __shared__ float b1_ld[2816];
    __shared__ float h_ld[512];
    __shared__ float x_ld[256];
    __shared__ float f_ld[512];
    __shared__ float o_ld[512];
    __shared__ float c_ld[512];
    __shared__ __align__(16) h2 hx_h2[256];
    __shared__ __align__(16) h2 x16_h2[128];
    __shared__ __align__(16) h2 modx_h2[128];

    const int tid = threadIdx.x;
    const int b   = blockIdx.x;
    const int j0  = tid * 4;
    const int c   = j0 % 44;
    const bool hasx = (c < 32) || (c >= 40);
    const int Jx0 = (j0 / 44) * 36 + (c < 32 ? c : c - 8);

    for (int j = tid; j < 2816; j += 704) b1_ld[j] = b1g[j];
    if (tid < 512) {
        h_ld[tid] = h0[b * 512 + tid];
        c_ld[tid] = c0[b * 512 + tid];
    }
    __syncthreads();

    const f4* __restrict__ w1r = (const f4*)(W1 + (size_t)j0 * 512);
    const float* __restrict__ xrow = x + (size_t)b * TT * DD;
    float* __restrict__ orow = out + (size_t)b * TT * UU;

    for (int t = 0; t < TT; ++t) {
        if (tid < 256) {
            h2 p; p[0] = (_Float16)h_ld[2 * tid]; p[1] = (_Float16)h_ld[2 * tid + 1];
            hx_h2[tid] = p;
        } else if (tid < 384) {
            int i = tid - 256;
            float v0 = xrow[t * DD + 2 * i];
            float v1 = xrow[t * DD + 2 * i + 1];
            x_ld[2 * i] = v0; x_ld[2 * i + 1] = v1;
            h2 p; p[0] = (_Float16)v0; p[1] = (_Float16)v1;
            x16_h2[i] = p;
        }
        __syncthreads();

        float a0 = b1_ld[j0], a1 = b1_ld[j0 + 1], a2 = b1_ld[j0 + 2], a3 = b1_ld[j0 + 3];
        if (hasx) {
            const f4* xr0 = (const f4*)(WxT + (size_t)Jx0 * 256);
            const f4* xr1 = xr0 + 32;
            const f4* xr2 = xr0 + 64;
            const f4* xr3 = xr0 + 96;
            const f4* xv4 = (const f4*)x16_h2;
#pragma unroll 4
            for (int kc = 0; kc < 32; ++kc) {
                f4 xv = xv4[kc];
                f4 w0 = xr0[kc], w1 = xr1[kc], w2 = xr2[kc], w3 = xr3[kc];
                const h2* xpv = (const h2*)&xv;
                const h2* p0 = (const h2*)&w0; const h2* p1 = (const h2*)&w1;
                const h2* p2 = (const h2*)&w2; const h2* p3 = (const h2*)&w3;
#pragma unroll
                for (int u = 0; u < 4; ++u) {
                    a0 = __builtin_amdgcn_fdot2(p0[u], xpv[u], a0, false);
                    a1 = __builtin_amdgcn_fdot2(p1[u], xpv[u], a1, false);
                    a2 = __builtin_amdgcn_fdot2(p2[u], xpv[u], a2, false);
                    a3 = __builtin_amdgcn_fdot2(p3[u], xpv[u], a3, false);
                }
            }
        }
        {
            const f4* hx4 = (const f4*)hx_h2;
            const f4* r0 = w1r;
            const f4* r1 = w1r + 64;
            const f4* r2 = w1r + 128;
            const f4* r3 = w1r + 192;
#pragma unroll 4
            for (int kc = 0; kc < 64; ++kc) {
                f4 hv = hx4[kc];
                f4 w0 = r0[kc], w1 = r1[kc], w2 = r2[kc], w3 = r3[kc];
                const h2* hp = (const h2*)&hv;
                const h2* p0 = (const h2*)&w0; const h2* p1 = (const h2*)&w1;
                const h2* p2 = (const h2*)&w2; const h2* p3 = (const h2*)&w3;
#pragma unroll
                for (int u = 0; u < 4; ++u) {
                    a0 = __builtin_amdgcn_fdot2(p0[u], hp[u], a0, false);
                    a1 = __builtin_amdgcn_fdot2(p1[u], hp[u], a1, false);
                    a2 = __builtin_amdgcn_fdot2(p2[u], hp[u], a2, false);
                    a3 = __builtin_amdgcn_fdot2(p3[u], hp[u], a3, false);
                }
            }
        }
        g_ld[j0] = a0; g_ld[j0 + 1] = a1; g_ld[j0 + 2] = a2; g_ld[j0 + 3] = a3;
        __syncthreads();

        if (tid < 128) {
            float m0 = sigf(g_ld[pkm(2 * tid)]);
            float m1 = sigf(g_ld[pkm(2 * tid + 1)]);
            h2 p;
            p[0] = (_Float16)(m0 * x_ld[2 * tid]);
            p[1] = (_Float16)(m1 * x_ld[2 * tid + 1]);
            modx_h2[tid] = p;
        } else if (tid < 640) {
            int u = tid - 128;
            float fs = sigf(g_ld[pk5(0, u)]);
            float fl = sigf(g_ld[pk5(1, u)]);
            float al = sigf(g_ld[pk5(2, u)]);
            f_ld[u] = al * fs + (1.0f - al) * fl;
            o_ld[u] = sigf(g_ld[pk5(3, u)]);
        }
        __syncthreads();

        if (tid < 512) {
            float s = g_ld[pk5(4, tid)];
            const f4* w2r = (const f4*)(W2 + (size_t)tid * 256);
            const f4* mx4 = (const f4*)modx_h2;
#pragma unroll 4
            for (int kc = 0; kc < 32; ++kc) {
                f4 wv = w2r[kc];
                f4 mv = mx4[kc];
                const h2* wp = (const h2*)&wv;
                const h2* mp = (const h2*)&mv;
#pragma unroll
                for (int u = 0; u < 4; ++u)
                    s = __builtin_amdgcn_fdot2(wp[u], mp[u], s, false);
            }
            float ch = tanhfast(s);
            float f  = f_ld[tid];
            float cc = f * c_ld[tid] + (1.0f - f) * ch;
            c_ld[tid] = cc;
            float h  = o_ld[tid] * tanhfast(cc);
            h_ld[tid] = h;
            orow[t * UU + tid] = h;
        }
        __syncthreads();
    }
}

// =====================================================================
extern "C" void kernel_launch(void* const* d_in, const int* in_sizes, int n_in,
                              void* d_out, int out_size, void* d_ws, size_t ws_size,
                              hipStream_t stream)
{
    (void)in_sizes; (void)n_in; (void)out_size;
    const float* x   = (const float*)d_in[0];
    const float* h0  = (const float*)d_in[1];
    const float* c0  = (const float*)d_in[2];
    const float* Wfs = (const float*)d_in[3];
    const float* bfs = (const float*)d_in[4];
    const float* Wfl = (const float*)d_in[5];
    const float* bfl = (const float*)d_in[6];
    const float* Wal = (const float*)d_in[7];
    const float* bal = (const float*)d_in[8];
    const float* Wm  = (const float*)d_in[9];
    const float* bm  = (const float*)d_in[10];
    const float* WC  = (const float*)d_in[11];
    const float* bC  = (const float*)d_in[12];
    const float* Wo  = (const float*)d_in[13];
    const float* bo  = (const float*)d_in[14];

    char* ws = (char*)d_ws;
    _Float16* W1   = (_Float16*)(ws + OFF_W1);
    _Float16* W2   = (_Float16*)(ws + OFF_W2);
    _Float16* WxT  = (_Float16*)(ws + OFF_WX);
    float*    b1   = (float*)   (ws + OFF_B1);
    _Float16* hbuf = (_Float16*)(ws + OFF_HB);
    _Float16* mxbf = (_Float16*)(ws + OFF_MX);
    u32*      ctr  = (u32*)     (ws + OFF_CTR);
    _Float16* Xpre = (_Float16*)(ws + OFF_XPRE);

    repack_kernel<<<dim3(1024), dim3(256), 0, stream>>>(
        Wfs, Wfl, Wal, Wm, WC, Wo, bfs, bfl, bal, bm, bC, bo, W1, W2, WxT, b1, ctr);

    if (ws_size >= WS_FULL) {
        xpre_kernel<<<dim3(256, 18), dim3(256), 0, stream>>>(x, WxT, Xpre);
        rnn_coop<<<dim3(NBLK), dim3(256), 0, stream>>>(
            x, h0, c0, W1, W2, b1, Xpre, hbuf, mxbf, ctr, (float*)d_out);
    } else {
        rnn_fb<<<dim3(BB), dim3(704), 0, stream>>>(
            x, h0, c0, W1, W2, WxT, b1, (float*)d_out);
    }
}

// Round 5
// 4382.710 us; speedup vs baseline: 10.4080x; 2.1159x over previous
//
#include <hip/hip_runtime.h>
#include <hip/hip_fp16.h>
#include <math.h>

typedef _Float16 h2 __attribute__((ext_vector_type(2)));
typedef _Float16 h8 __attribute__((ext_vector_type(8)));
typedef float    f4 __attribute__((ext_vector_type(4)));
typedef unsigned short     u16;
typedef unsigned int       u32;
typedef unsigned long long u64;

#define BB 64
#define TT 512
#define DD 256
#define UU 512

#define NBLK 64
#define CPB  44   // packed gate-cols per block: 8*{fs,fl,al,o,WCh} + 4 m
#define XPB  36   // of those, cols with an x-contribution (32 gate + 4 m)
#define UPB  8    // h/c columns owned per block
#define MPB  4    // m (x-dim) columns owned per block
#define NJ   2816
#define NJX  2304

// ---------- ws layout (bytes) ----------
#define OFF_W1   0ull                              // f16 [2816][512] packed, K-contig
#define OFF_W2   (OFF_W1 + 2816ull*512*2)          // f16 [512][256]
#define OFF_WX   (OFF_W2 + 512ull*256*2)           // f16 [2304][256] packed
#define OFF_B1   (OFF_WX + 2304ull*256*2)          // f32 [2816] packed
#define OFF_HB   (OFF_B1 + 2816ull*4)              // f16 [64][512]  h state
#define OFF_MX   (OFF_HB + 64ull*512*2)            // f16 [64][256]  mod_x
#define OFF_CTR  (OFF_MX + 64ull*256*2)            // u32 [1025*16] counters (1/line)
#define OFF_XPRE (OFF_CTR + 16400ull*4)            // f16 [512][2304][64]
#define WS_FULL  (OFF_XPRE + 512ull*2304*64*2)     // ~155.5 MB

__device__ __forceinline__ float sigf(float v)     { return 1.0f / (1.0f + __expf(-v)); }
__device__ __forceinline__ float tanhfast(float v) { return 1.0f - 2.0f / (__expf(2.0f * v) + 1.0f); }

// leader waits until ctr reaches NBLK. Relaxed polls (no cache ops); ONE
// acquire load at the end emits the single buffer_inv (L1+XCD-L2) that makes
// the producers' LLC-resident data visible to this block's cached loads.
__device__ __forceinline__ void wait_ctr(u32* c) {
    u32 it = 0;
    while (__hip_atomic_load(c, __ATOMIC_RELAXED, __HIP_MEMORY_SCOPE_AGENT) < (u32)NBLK) {
        __builtin_amdgcn_s_sleep(2);
        if (++it > 4000000u) break;   // safety valve
    }
    (void)__hip_atomic_load(c, __ATOMIC_ACQUIRE, __HIP_MEMORY_SCOPE_AGENT);  // buffer_inv
}

// packed-order helpers (fallback path)
__device__ __forceinline__ int pk5(int g, int u) { return (u >> 3) * 44 + g * 8 + (u & 7); }
__device__ __forceinline__ int pkm(int d)        { return (d >> 2) * 44 + 40 + (d & 3); }

// =====================================================================
// Kernel 1: repack weights into packed block-sliced f16 layouts + zero ctrs
// =====================================================================
__global__ void repack_kernel(const float* __restrict__ Wfs, const float* __restrict__ Wfl,
                              const float* __restrict__ Wal, const float* __restrict__ Wm,
                              const float* __restrict__ WC,  const float* __restrict__ Wo,
                              const float* __restrict__ bfs, const float* __restrict__ bfl,
                              const float* __restrict__ bal, const float* __restrict__ bm,
                              const float* __restrict__ bC,  const float* __restrict__ bo,
                              _Float16* __restrict__ W1, _Float16* __restrict__ W2,
                              _Float16* __restrict__ WxT, float* __restrict__ b1,
                              u32* __restrict__ ctr)
{
    const int stride = gridDim.x * blockDim.x;
    const int idx = blockIdx.x * blockDim.x + threadIdx.x;

    for (int i = idx; i < 2816 * 512; i += stride) {
        int J = i >> 9, k = i & 511;
        int blk = J / 44, c = J - blk * 44;
        float v;
        if (c < 40) {
            int grp = c >> 3, u = blk * 8 + (c & 7);
            const float* Wg = (grp == 0) ? Wfs : (grp == 1) ? Wfl : (grp == 2) ? Wal : (grp == 3) ? Wo : WC;
            v = Wg[(size_t)k * 512 + u];
        } else {
            int d = blk * 4 + (c - 40);
            v = Wm[(size_t)k * 256 + d];
        }
        W1[i] = (_Float16)v;
    }
    for (int i = idx; i < 512 * 256; i += stride) {
        int u = i >> 8, dd = i & 255;
        W2[i] = (_Float16)WC[(size_t)(512 + dd) * 512 + u];
    }
    for (int i = idx; i < 2304 * 256; i += stride) {
        int Jx = i >> 8, k2 = i & 255;
        int blk = Jx / 36, lc = Jx - blk * 36;
        float v;
        if (lc < 32) {
            int grp = lc >> 3, u = blk * 8 + (lc & 7);
            const float* Wg = (grp == 0) ? Wfs : (grp == 1) ? Wfl : (grp == 2) ? Wal : Wo;
            v = Wg[(size_t)(512 + k2) * 512 + u];
        } else {
            int d = blk * 4 + (lc - 32);
            v = Wm[(size_t)(512 + k2) * 256 + d];
        }
        WxT[i] = (_Float16)v;
    }
    for (int J = idx; J < 2816; J += stride) {
        int blk = J / 44, c = J - blk * 44;
        float v;
        if (c < 40) {
            int grp = c >> 3, u = blk * 8 + (c & 7);
            v = (grp == 0) ? bfs[u] : (grp == 1) ? bfl[u] : (grp == 2) ? bal[u] : (grp == 3) ? bo[u] : bC[u];
        } else {
            v = bm[blk * 4 + (c - 40)];
        }
        b1[J] = v;
    }
    for (int i = idx; i < 16400; i += stride) ctr[i] = 0;
}

// =====================================================================
// Kernel 2: Xpre = x @ W_x via MFMA.  [32768,256]@[256,2304] -> f16
// output layout [t][Jx][b].
// =====================================================================
__global__ __launch_bounds__(256) void xpre_kernel(const float* __restrict__ x,
                                                   const _Float16* __restrict__ WxT,
                                                   _Float16* __restrict__ Xpre)
{
    __shared__ _Float16 As[128 * 32];
    __shared__ _Float16 Bs[128 * 32];

    const int tid  = threadIdx.x;
    const int lane = tid & 63;
    const int w    = tid >> 6;
    const int wm   = w >> 1, wn = w & 1;
    const int quad = lane >> 4, l16 = lane & 15;
    const int row0 = blockIdx.x * 128;
    const int n0   = blockIdx.y * 128;

    f4 acc[4][4];
    for (int i = 0; i < 4; ++i)
        for (int j = 0; j < 4; ++j)
            acc[i][j] = (f4){0.f, 0.f, 0.f, 0.f};

    for (int kt = 0; kt < 8; ++kt) {
        const int k0 = kt * 32;
        {
            int r  = tid >> 3;
            int cg = (tid & 7) * 4;
            for (int rr = r; rr < 128; rr += 32) {
                f4 v = *(const f4*)&x[(size_t)(row0 + rr) * 256 + k0 + cg];
                As[rr * 32 + cg + 0] = (_Float16)v.x;
                As[rr * 32 + cg + 1] = (_Float16)v.y;
                As[rr * 32 + cg + 2] = (_Float16)v.z;
                As[rr * 32 + cg + 3] = (_Float16)v.w;
            }
        }
        {
            int r   = tid & 127;
            int seg = (tid >> 7) * 16;
            const _Float16* src = &WxT[(size_t)(n0 + r) * 256 + k0 + seg];
            *(f4*)&Bs[r * 32 + seg]     = *(const f4*)src;
            *(f4*)&Bs[r * 32 + seg + 8] = *(const f4*)(src + 8);
        }
        __syncthreads();

        h8 af[4], bf[4];
#pragma unroll
        for (int f = 0; f < 4; ++f) {
            af[f] = *(const h8*)&As[(wm * 64 + f * 16 + l16) * 32 + quad * 8];
            bf[f] = *(const h8*)&Bs[(wn * 64 + f * 16 + l16) * 32 + quad * 8];
        }
#pragma unroll
        for (int fm = 0; fm < 4; ++fm)
#pragma unroll
            for (int fn = 0; fn < 4; ++fn)
                acc[fm][fn] = __builtin_amdgcn_mfma_f32_16x16x32_f16(af[fm], bf[fn], acc[fm][fn], 0, 0, 0);
        __syncthreads();
    }

#pragma unroll
    for (int fm = 0; fm < 4; ++fm)
#pragma unroll
        for (int fn = 0; fn < 4; ++fn)
#pragma unroll
            for (int r = 0; r < 4; ++r) {
                int rr = row0 + wm * 64 + fm * 16 + quad * 4 + r;  // x row = b*T+t
                int J  = n0 + wn * 64 + fn * 16 + l16;
                int b = rr >> 9, tt = rr & 511;
                Xpre[((size_t)tt * NJX + J) * 64 + b] = (_Float16)acc[fm][fn][r];
            }
}

// =====================================================================
// Kernel 3: cooperative recurrent scan, flag-signaled (no symmetric
// barrier, no wbl2). 64 blocks x 256 thr. Per step:
//   wait h-ctr[t-1] -> bf regs from L2 -> acc2 (WCh+m cols) -> publish
//   mod_x early (atomic->LLC) + fire mx-ctr -> acc0/acc1 -> elementwise
//   -> wait mx-ctr -> GEMM2 from L2 -> update -> publish h + fire h-ctr.
// =====================================================================
__global__ __launch_bounds__(256, 1) void rnn_coop(
    const float* __restrict__ x, const float* __restrict__ h0, const float* __restrict__ c0,
    const _Float16* __restrict__ W1, const _Float16* __restrict__ W2,
    const float* __restrict__ b1, const _Float16* __restrict__ Xpre,
    _Float16* __restrict__ hbuf, _Float16* __restrict__ mxbuf, u32* __restrict__ ctr,
    float* __restrict__ out)
{
    __shared__ __align__(16) _Float16 sW1[48 * 512];  // 48 KB, resident all steps
    __shared__ float sS[48 * 68];                     // stride 68: 2-way max (free)
    __shared__ float sF[8 * 64];
    __shared__ float sO[8 * 64];
    __shared__ float sCP[8 * 64];
    __shared__ float sC[8 * 64];
    __shared__ float sB1[44];

    const int tid  = threadIdx.x;
    const int blk  = blockIdx.x;
    const int lane = tid & 63;
    const int w    = tid >> 6;
    const int l16  = lane & 15;
    const int quad = lane >> 4;
    const int swz  = l16 & 7;
    const int br   = w * 16 + l16;   // batch row owned in MFMA B-frags

    // ---- stage W1 slice (44 rows + 4 zero-pad) with chunk swizzle ----
    for (int idx = tid; idx < 48 * 64; idx += 256) {
        int r = idx >> 6, j = idx & 63;
        h8 v = {};
        if (r < CPB) v = *(const h8*)(W1 + ((size_t)(blk * CPB + r) * 512 + j * 8));
        *(h8*)&sW1[(r * 64 + (j ^ (r & 7))) * 8] = v;
    }
    // ---- W2 A-frags in registers for all steps (rows u<8, pad to 16) ----
    h8 af2[8];
#pragma unroll
    for (int ks = 0; ks < 8; ++ks) {
        af2[ks] = (h8){};
        if (l16 < 8)
            af2[ks] = *(const h8*)(W2 + (size_t)(blk * UPB + l16) * 256 + ks * 32 + quad * 8);
    }
    if (tid < CPB) sB1[tid] = b1[blk * CPB + tid];
    // ---- init c (block-local) ----
    for (int idx = tid; idx < UPB * 64; idx += 256) {
        int u = idx >> 6, b = idx & 63;
        sC[u * 64 + b] = c0[b * UU + blk * UPB + u];
    }
    // ---- publish our h0 slice straight to LLC (atomic stores) ----
    if (tid < 128) {
        int q = tid >> 6, b = tid & 63;
        _Float16 hp[4];
#pragma unroll
        for (int r = 0; r < 4; ++r) hp[r] = (_Float16)h0[b * UU + blk * UPB + q * 4 + r];
        u64 hq; __builtin_memcpy(&hq, hp, 8);
        __hip_atomic_store((u64*)(hbuf + (size_t)b * 512 + blk * UPB + q * 4), hq,
                           __ATOMIC_RELAXED, __HIP_MEMORY_SCOPE_AGENT);
    }
    __syncthreads();                      // drains vmcnt: publishes at LLC
    if (tid == 0) {
        __hip_atomic_fetch_add(&ctr[1024 * 16], 1u, __ATOMIC_RELAXED, __HIP_MEMORY_SCOPE_AGENT);
        wait_ctr(&ctr[1024 * 16]);        // all h0 slices visible; inv
    }
    __syncthreads();

    for (int t = 0; t < TT; ++t) {
        // ---- prefetch read-only operands (overlap the h wait) ----
        const _Float16* xp = Xpre + ((size_t)t * NJX + blk * XPB) * 64;
        float pfs[2], pfl[2], pal[2], pov[2];
#pragma unroll
        for (int i = 0; i < 2; ++i) {
            int u = w * 2 + i;
            pfs[i] = (float)xp[(size_t)u * 64 + lane];
            pfl[i] = (float)xp[(size_t)(8 + u) * 64 + lane];
            pal[i] = (float)xp[(size_t)(16 + u) * 64 + lane];
            pov[i] = (float)xp[(size_t)(24 + u) * 64 + lane];
        }
        float pxm0 = 0.f, pxm1 = 0.f, pxv0 = 0.f, pxv1 = 0.f;
        int dp = tid >> 6, bm = tid & 63;
        if (tid < 128) {
            pxm0 = (float)xp[(size_t)(32 + 2 * dp) * 64 + bm];
            pxm1 = (float)xp[(size_t)(33 + 2 * dp) * 64 + bm];
            pxv0 = x[((size_t)bm * TT + t) * DD + blk * MPB + 2 * dp];
            pxv1 = x[((size_t)bm * TT + t) * DD + blk * MPB + 2 * dp + 1];
        }

        // ---- wait for h[t-1] from all blocks (leader poll + single inv) ----
        if (t > 0) {
            if (tid == 0) wait_ctr(&ctr[(2 * (t - 1) + 1) * 16]);
            __syncthreads();
        }

        // ---- B-frags: h[b][k] straight from L2 into registers ----
        h8 bf[16];
#pragma unroll
        for (int ks = 0; ks < 16; ++ks)
            bf[ks] = *(const h8*)(hbuf + (size_t)br * 512 + (ks * 4 + quad) * 8);

        // ---- acc2 first: cols 32..47 = WCh(32..39) + m(40..43) ----
        f4 acc2 = {0.f, 0.f, 0.f, 0.f};
#pragma unroll
        for (int ks = 0; ks < 16; ++ks) {
            int jx = (ks * 4 + quad) ^ swz;
            h8 a2 = *(const h8*)&sW1[((32 + l16) * 64 + jx) * 8];
            acc2 = __builtin_amdgcn_mfma_f32_16x16x32_f16(a2, bf[ks], acc2, 0, 0, 0);
        }
#pragma unroll
        for (int r = 0; r < 4; ++r)
            sS[(32 + quad * 4 + r) * 68 + br] = acc2[r];
        __syncthreads();

        // ---- mod_x: compute + publish early (atomic -> LLC), fire ctr ----
        if (tid < 128) {
            float mr0 = sS[(40 + 2 * dp) * 68 + bm] + sB1[40 + 2 * dp] + pxm0;
            float mr1 = sS[(41 + 2 * dp) * 68 + bm] + sB1[41 + 2 * dp] + pxm1;
            _Float16 m0 = (_Float16)(sigf(mr0) * pxv0);
            _Float16 m1 = (_Float16)(sigf(mr1) * pxv1);
            u16 a, b2; __builtin_memcpy(&a, &m0, 2); __builtin_memcpy(&b2, &m1, 2);
            u32 pk = (u32)a | ((u32)b2 << 16);
            __hip_atomic_store((u32*)(mxbuf + (size_t)bm * 256 + blk * MPB + 2 * dp), pk,
                               __ATOMIC_RELAXED, __HIP_MEMORY_SCOPE_AGENT);
        }
        __syncthreads();                  // drains vmcnt: mx slice at LLC
        if (tid == 0)
            __hip_atomic_fetch_add(&ctr[(2 * t) * 16], 1u, __ATOMIC_RELAXED, __HIP_MEMORY_SCOPE_AGENT);

        // ---- acc0/acc1: cols 0..31 (fs,fl,al,o), reuse bf regs ----
        f4 acc0 = {0.f, 0.f, 0.f, 0.f}, acc1 = {0.f, 0.f, 0.f, 0.f};
#pragma unroll
        for (int ks = 0; ks < 16; ++ks) {
            int jx = (ks * 4 + quad) ^ swz;
            h8 a0 = *(const h8*)&sW1[((     l16) * 64 + jx) * 8];
            h8 a1 = *(const h8*)&sW1[((16 + l16) * 64 + jx) * 8];
            acc0 = __builtin_amdgcn_mfma_f32_16x16x32_f16(a0, bf[ks], acc0, 0, 0, 0);
            acc1 = __builtin_amdgcn_mfma_f32_16x16x32_f16(a1, bf[ks], acc1, 0, 0, 0);
        }
#pragma unroll
        for (int r = 0; r < 4; ++r) {
            sS[(     quad * 4 + r) * 68 + br] = acc0[r];
            sS[(16 + quad * 4 + r) * 68 + br] = acc1[r];
        }
        __syncthreads();

        // ---- elementwise: f/o gates + cpre ----
#pragma unroll
        for (int i = 0; i < 2; ++i) {
            int u = w * 2 + i;
            float fs = sigf(sS[u * 68 + lane]        + sB1[u]      + pfs[i]);
            float fl = sigf(sS[(8 + u) * 68 + lane]  + sB1[8 + u]  + pfl[i]);
            float al = sigf(sS[(16 + u) * 68 + lane] + sB1[16 + u] + pal[i]);
            sF[u * 64 + lane]  = al * fs + (1.0f - al) * fl;
            sO[u * 64 + lane]  = sigf(sS[(24 + u) * 68 + lane] + sB1[24 + u] + pov[i]);
            sCP[u * 64 + lane] = sS[(32 + u) * 68 + lane] + sB1[32 + u];
        }
        __syncthreads();

        // ---- wait mod_x from all blocks (usually already complete) ----
        if (tid == 0) wait_ctr(&ctr[(2 * t) * 16]);
        __syncthreads();

        // ---- GEMM2: W2(regs) x mod_x(L2) ; state update; publish h ----
        {
            f4 aq = {0.f, 0.f, 0.f, 0.f};
#pragma unroll
            for (int ks = 0; ks < 8; ++ks) {
                h8 bf2 = *(const h8*)(mxbuf + (size_t)br * 256 + (ks * 4 + quad) * 8);
                aq = __builtin_amdgcn_mfma_f32_16x16x32_f16(af2[ks], bf2, aq, 0, 0, 0);
            }
            if (quad < 2) {
                int u0 = quad * 4;
                float hv[4];
#pragma unroll
                for (int r = 0; r < 4; ++r) {
                    int u = u0 + r;
                    float ch = tanhfast(aq[r] + sCP[u * 64 + br]);
                    float f  = sF[u * 64 + br];
                    float c  = f * sC[u * 64 + br] + (1.0f - f) * ch;
                    sC[u * 64 + br] = c;
                    hv[r] = sO[u * 64 + br] * tanhfast(c);
                }
                _Float16 hp[4] = {(_Float16)hv[0], (_Float16)hv[1], (_Float16)hv[2], (_Float16)hv[3]};
                u64 hq; __builtin_memcpy(&hq, hp, 8);
                __hip_atomic_store((u64*)(hbuf + (size_t)br * 512 + blk * UPB + u0), hq,
                                   __ATOMIC_RELAXED, __HIP_MEMORY_SCOPE_AGENT);
                f4 ovec = {hv[0], hv[1], hv[2], hv[3]};
                __builtin_nontemporal_store(ovec, (f4*)&out[((size_t)br * TT + t) * UU + blk * UPB + u0]);
            }
        }
        __syncthreads();                  // drains vmcnt: h slice at LLC
        if (tid == 0)
            __hip_atomic_fetch_add(&ctr[(2 * t + 1) * 16], 1u, __ATOMIC_RELAXED, __HIP_MEMORY_SCOPE_AGENT);
    }
}

// =====================================================================
// Fallback (small ws): per-batch dot2 scan on packed weights.
// =====================================================================
__global__ __launch_bounds__(704) void rnn_fb(const float* __restrict__ x,
                                              const float* __restrict__ h0,
                                              const float* __restrict__ c0,
                                              const _Float16* __restrict__ W1,
                                              const _Float16* __restrict__ W2,
                                              const _Float16* __restrict__ WxT,
                                              const float* __restrict__ b1g,
                                              float* __restrict__ out)
{
    __shared__ float g_ld[2816];
    __shared__ float b1_ld[2816];
    __shared__ float h_ld[512];
    __shared__ float x_ld[256];
    __shared__ float f_ld[512];
    __shared__ float o_ld[512];
    __shared__ float c_ld[512];
    __shared__ __align__(16) h2 hx_h2[256];
    __shared__ __align__(16) h2 x16_h2[128];
    __shared__ __align__(16) h2 modx_h2[128];

    const int tid = threadIdx.x;
    const int b   = blockIdx.x;
    const int j0  = tid * 4;
    const int c   = j0 % 44;
    const bool hasx = (c < 32) || (c >= 40);
    const int Jx0 = (j0 / 44) * 36 + (c < 32 ? c : c - 8);

    for (int j = tid; j < 2816; j += 704) b1_ld[j] = b1g[j];
    if (tid < 512) {
        h_ld[tid] = h0[b * 512 + tid];
        c_ld[tid] = c0[b * 512 + tid];
    }
    __syncthreads();

    const f4* __restrict__ w1r = (const f4*)(W1 + (size_t)j0 * 512);
    const float* __restrict__ xrow = x + (size_t)b * TT * DD;
    float* __restrict__ orow = out + (size_t)b * TT * UU;

    for (int t = 0; t < TT; ++t) {
        if (tid < 256) {
            h2 p; p[0] = (_Float16)h_ld[2 * tid]; p[1] = (_Float16)h_ld[2 * tid + 1];
            hx_h2[tid] = p;
        } else if (tid < 384) {
            int i = tid - 256;
            float v0 = xrow[t * DD + 2 * i];
            float v1 = xrow[t * DD + 2 * i + 1];
            x_ld[2 * i] = v0; x_ld[2 * i + 1] = v1;
            h2 p; p[0] = (_Float16)v0; p[1] = (_Float16)v1;
            x16_h2[i] = p;
        }
        __syncthreads();

        float a0 = b1_ld[j0], a1 = b1_ld[j0 + 1], a2 = b1_ld[j0 + 2], a3 = b1_ld[j0 + 3];
        if (hasx) {
            const f4* xr0 = (const f4*)(WxT + (size_t)Jx0 * 256);
            const f4* xr1 = xr0 + 32;
            const f4* xr2 = xr0 + 64;
            const f4* xr3 = xr0 + 96;
            const f4* xv4 = (const f4*)x16_h2;
#pragma unroll 4
            for (int kc = 0; kc < 32; ++kc) {
                f4 xv = xv4[kc];
                f4 w0 = xr0[kc], w1 = xr1[kc], w2 = xr2[kc], w3 = xr3[kc];
                const h2* xpv = (const h2*)&xv;
                const h2* p0 = (const h2*)&w0; const h2* p1 = (const h2*)&w1;
                const h2* p2 = (const h2*)&w2; const h2* p3 = (const h2*)&w3;
#pragma unroll
                for (int u = 0; u < 4; ++u) {
                    a0 = __builtin_amdgcn_fdot2(p0[u], xpv[u], a0, false);
                    a1 = __builtin_amdgcn_fdot2(p1[u], xpv[u], a1, false);
                    a2 = __builtin_amdgcn_fdot2(p2[u], xpv[u], a2, false);
                    a3 = __builtin_amdgcn_fdot2(p3[u], xpv[u], a3, false);
                }
            }
        }
        {
            const f4* hx4 = (const f4*)hx_h2;
            const f4* r0 = w1r;
            const f4* r1 = w1r + 64;
            const f4* r2 = w1r + 128;
            const f4* r3 = w1r + 192;
#pragma unroll 4
            for (int kc = 0; kc < 64; ++kc) {
                f4 hv = hx4[kc];
                f4 w0 = r0[kc], w1 = r1[kc], w2 = r2[kc], w3 = r3[kc];
                const h2* hp = (const h2*)&hv;
                const h2* p0 = (const h2*)&w0; const h2* p1 = (const h2*)&w1;
                const h2* p2 = (const h2*)&w2; const h2* p3 = (const h2*)&w3;
#pragma unroll
                for (int u = 0; u < 4; ++u) {
                    a0 = __builtin_amdgcn_fdot2(p0[u], hp[u], a0, false);
                    a1 = __builtin_amdgcn_fdot2(p1[u], hp[u], a1, false);
                    a2 = __builtin_amdgcn_fdot2(p2[u], hp[u], a2, false);
                    a3 = __builtin_amdgcn_fdot2(p3[u], hp[u], a3, false);
                }
            }
        }
        g_ld[j0] = a0; g_ld[j0 + 1] = a1; g_ld[j0 + 2] = a2; g_ld[j0 + 3] = a3;
        __syncthreads();

        if (tid < 128) {
            float m0 = sigf(g_ld[pkm(2 * tid)]);
            float m1 = sigf(g_ld[pkm(2 * tid + 1)]);
            h2 p;
            p[0] = (_Float16)(m0 * x_ld[2 * tid]);
            p[1] = (_Float16)(m1 * x_ld[2 * tid + 1]);
            modx_h2[tid] = p;
        } else if (tid < 640) {
            int u = tid - 128;
            float fs = sigf(g_ld[pk5(0, u)]);
            float fl = sigf(g_ld[pk5(1, u)]);
            float al = sigf(g_ld[pk5(2, u)]);
            f_ld[u] = al * fs + (1.0f - al) * fl;
            o_ld[u] = sigf(g_ld[pk5(3, u)]);
        }
        __syncthreads();

        if (tid < 512) {
            float s = g_ld[pk5(4, tid)];
            const f4* w2r = (const f4*)(W2 + (size_t)tid * 256);
            const f4* mx4 = (const f4*)modx_h2;
#pragma unroll 4
            for (int kc = 0; kc < 32; ++kc) {
                f4 wv = w2r[kc];
                f4 mv = mx4[kc];
                const h2* wp = (const h2*)&wv;
                const h2* mp = (const h2*)&mv;
#pragma unroll
                for (int u = 0; u < 4; ++u)
                    s = __builtin_amdgcn_fdot2(wp[u], mp[u], s, false);
            }
            float ch = tanhfast(s);
            float f  = f_ld[tid];
            float cc = f * c_ld[tid] + (1.0f - f) * ch;
            c_ld[tid] = cc;
            float h  = o_ld[tid] * tanhfast(cc);
            h_ld[tid] = h;
            orow[t * UU + tid] = h;
        }
        __syncthreads();
    }
}

// =====================================================================
extern "C" void kernel_launch(void* const* d_in, const int* in_sizes, int n_in,
                              void* d_out, int out_size, void* d_ws, size_t ws_size,
                              hipStream_t stream)
{
    (void)in_sizes; (void)n_in; (void)out_size;
    const float* x   = (const float*)d_in[0];
    const float* h0  = (const float*)d_in[1];
    const float* c0  = (const float*)d_in[2];
    const float* Wfs = (const float*)d_in[3];
    const float* bfs = (const float*)d_in[4];
    const float* Wfl = (const float*)d_in[5];
    const float* bfl = (const float*)d_in[6];
    const float* Wal = (const float*)d_in[7];
    const float* bal = (const float*)d_in[8];
    const float* Wm  = (const float*)d_in[9];
    const float* bm  = (const float*)d_in[10];
    const float* WC  = (const float*)d_in[11];
    const float* bC  = (const float*)d_in[12];
    const float* Wo  = (const float*)d_in[13];
    const float* bo  = (const float*)d_in[14];

    char* ws = (char*)d_ws;
    _Float16* W1   = (_Float16*)(ws + OFF_W1);
    _Float16* W2   = (_Float16*)(ws + OFF_W2);
    _Float16* WxT  = (_Float16*)(ws + OFF_WX);
    float*    b1   = (float*)   (ws + OFF_B1);
    _Float16* hbuf = (_Float16*)(ws + OFF_HB);
    _Float16* mxbf = (_Float16*)(ws + OFF_MX);
    u32*      ctr  = (u32*)     (ws + OFF_CTR);
    _Float16* Xpre = (_Float16*)(ws + OFF_XPRE);

    repack_kernel<<<dim3(1024), dim3(256), 0, stream>>>(
        Wfs, Wfl, Wal, Wm, WC, Wo, bfs, bfl, bal, bm, bC, bo, W1, W2, WxT, b1, ctr);

    if (ws_size >= WS_FULL) {
        xpre_kernel<<<dim3(256, 18), dim3(256), 0, stream>>>(x, WxT, Xpre);
        rnn_coop<<<dim3(NBLK), dim3(256), 0, stream>>>(
            x, h0, c0, W1, W2, b1, Xpre, hbuf, mxbf, ctr, (float*)d_out);
    } else {
        rnn_fb<<<dim3(BB), dim3(704), 0, stream>>>(
            x, h0, c0, W1, W2, WxT, b1, (float*)d_out);
    }
}